// Round 4
// baseline (568.906 us; speedup 1.0000x reference)
//
#include <hip/hip_runtime.h>
#include <math.h>

#define N_NODES 50000
#define N_EDGES 800000
#define F_IN    128
#define HID     64
#define N_CLS   40

#define M1 (3 * HID)    // 192: [W1_0 | W1_1 | root1]
#define M2P 128         // padded 120: [W2_0 | W2_1 | root2 | 0pad]

#define SLOTS 40        // edata slots per node (max observed deg ~36, Poisson λ=16)
#define NRB 129         // permute range-blocks
#define NR  390         // nodes per range-block (129*390 = 50310 >= 50000)

#define NW 32768        // weight elements in concat_w: M1*F_IN + M2P*HID

using sh8 = __attribute__((ext_vector_type(8))) short;
using floatx4 = __attribute__((ext_vector_type(4))) float;

__device__ inline unsigned short f2bf(float f) {
    union { float f; unsigned int u; } c{f};
    unsigned int r = (c.u + 0x7FFF + ((c.u >> 16) & 1)) >> 16;
    return (unsigned short)r;
}
__device__ inline float bf2f(unsigned int u) {
    union { unsigned int u; float f; } c;
    c.u = u << 16;
    return c.f;
}

// ---------------- weight concat (both layers) + edge-stream compression ----------
// ed16[e] = (u16)dst[e];  pay32[e] = (u16)src[e] | (u16 quantized attr << 16)
__global__ void concat_w(const float* __restrict__ W1, const float* __restrict__ root1,
                         const float* __restrict__ W2, const float* __restrict__ root2,
                         const int* __restrict__ src, const int* __restrict__ dst,
                         const float* __restrict__ attr,
                         unsigned short* __restrict__ WT1, unsigned short* __restrict__ WT2,
                         unsigned short* __restrict__ ed16, unsigned int* __restrict__ pay32) {
    int i = blockIdx.x * blockDim.x + threadIdx.x;
    if (i < M1 * F_IN) {
        int c = i / F_IN, k = i % F_IN;
        float val;
        if (c < HID)            val = W1[k * HID + c];
        else if (c < 2 * HID)   val = W1[F_IN * HID + k * HID + (c - HID)];
        else                    val = root1[k * HID + (c - 2 * HID)];
        WT1[i] = f2bf(val);
    } else if (i < NW) {
        int ii = i - M1 * F_IN;
        int c = ii / HID, k = ii % HID;
        float val;
        if (c < N_CLS)            val = W2[k * N_CLS + c];
        else if (c < 2 * N_CLS)   val = W2[HID * N_CLS + k * N_CLS + (c - N_CLS)];
        else if (c < 3 * N_CLS)   val = root2[k * N_CLS + (c - 2 * N_CLS)];
        else                      val = 0.0f;
        WT2[ii] = f2bf(val);
    } else {
        int e = i - NW;
        if (e < N_EDGES) {
            ed16[e] = (unsigned short)dst[e];
            unsigned int q = (unsigned int)(attr[e] * 65535.0f + 0.5f);
            pay32[e] = (unsigned int)src[e] | (q << 16);
        }
    }
}

// ---------------- LDS-staged bucketed permute: NO global atomics, NO partial-line
// scatters. Each block owns NR nodes; hist + 40-slot buckets live in LDS; each
// block scans the compressed u16 dst stream (1.6 MB, L3-resident) and writes its
// edata region once as full-line uint4 streams. cnt written directly (no zeroing
// pass, no RMW). -------------------------------------------------------------
__global__ __launch_bounds__(256) void perm_lds(const unsigned short* __restrict__ ed16,
                                                const unsigned int* __restrict__ pay32,
                                                int* __restrict__ cnt,
                                                unsigned int* __restrict__ edata) {
    __shared__ int hist[NR];                    // 1560 B
    __shared__ unsigned int led[NR * SLOTS];    // 62400 B  (total 63960 < 64 KB)

    int tid = threadIdx.x;
    int lo = blockIdx.x * NR;

    for (int i = tid; i < NR; i += 256) hist[i] = 0;
    __syncthreads();

    // scan all 800K destinations as uint4 (8 u16 per load), coalesced
    const uint4* d4 = (const uint4*)ed16;
    for (int i = tid; i < N_EDGES / 8; i += 256) {
        uint4 v = d4[i];
        int ebase = i * 8;
        unsigned int w[4] = {v.x, v.y, v.z, v.w};
#pragma unroll
        for (int h = 0; h < 4; ++h) {
#pragma unroll
            for (int s = 0; s < 2; ++s) {
                int d  = (int)((w[h] >> (s * 16)) & 0xffffu);
                int ld = d - lo;
                if ((unsigned)ld < (unsigned)NR) {
                    unsigned int pay = pay32[ebase + h * 2 + s];
                    int pos = atomicAdd(&hist[ld], 1);   // LDS atomic (CU-local)
                    if (pos < SLOTS) led[ld * SLOTS + pos] = pay;
                }
            }
        }
    }
    __syncthreads();

    int vn = N_NODES - lo;
    if (vn > NR) vn = NR;
    if (vn <= 0) return;

    // cnt: one clean write per node
    for (int i = tid; i < vn; i += 256) cnt[lo + i] = hist[i];

    // edata: vn*SLOTS uints as coalesced uint4 full-line streams
    uint4* out4 = (uint4*)(edata + (size_t)lo * SLOTS);
    const uint4* l4 = (const uint4*)led;
    int tot4 = vn * (SLOTS / 4);
    for (int i = tid; i < tot4; i += 256) out4[i] = l4[i];
}

// ---------------- shared gemm body: 64-row tile, A staged in LDS once,
// B fragments read DIRECTLY from global (WT is 16-48 KB, L2-resident).
// No Bs buffer -> 17.4 KB LDS (9 blocks/CU), one barrier total. --------------
template <int KD, bool AF32, int SPLIT, int PW, int ROOTW, int MT>
__device__ __forceinline__ void gemm_body(int bid, const void* __restrict__ Aptr,
                                          const unsigned short* __restrict__ Bt,
                                          unsigned short* __restrict__ Csp,
                                          float* __restrict__ Croot, int Crows) {
    constexpr int KP = KD + 8;
    __shared__ unsigned short As[64 * KP];

    int tid = threadIdx.x;
    int row0 = bid * 64;

    if (AF32) {
        const float* A = (const float*)Aptr;
        for (int c = tid; c < 64 * (KD / 4); c += 256) {
            int r = c / (KD / 4), q = c % (KD / 4);
            int gr = row0 + r;
            float4 v = make_float4(0.f, 0.f, 0.f, 0.f);
            if (gr < Crows) v = *(const float4*)(A + (size_t)gr * KD + q * 4);
            union { unsigned short s[4]; uint2 u; } pk;
            pk.s[0] = f2bf(v.x); pk.s[1] = f2bf(v.y);
            pk.s[2] = f2bf(v.z); pk.s[3] = f2bf(v.w);
            *(uint2*)&As[r * KP + q * 4] = pk.u;
        }
    } else {
        const unsigned short* A = (const unsigned short*)Aptr;
        for (int c = tid; c < 64 * (KD / 8); c += 256) {
            int r = c / (KD / 8), q = c % (KD / 8);
            int gr = row0 + r;
            sh8 v = {};
            if (gr < Crows) v = *(const sh8*)(A + (size_t)gr * KD + q * 8);
            *(sh8*)&As[r * KP + q * 8] = v;
        }
    }
    __syncthreads();  // the ONLY barrier in the kernel

    int wv = tid >> 6, lane = tid & 63;
    int lrow = lane & 15, lq = lane >> 4;

    for (int mt = 0; mt < MT; ++mt) {
        int c0 = mt * 64;

        floatx4 acc[4] = {{0.f,0.f,0.f,0.f},{0.f,0.f,0.f,0.f},{0.f,0.f,0.f,0.f},{0.f,0.f,0.f,0.f}};
#pragma unroll
        for (int kt = 0; kt < KD / 32; ++kt) {
            int kb = kt * 32 + lq * 8;
            sh8 a0 = *(const sh8*)&As[(wv * 16 + lrow) * KP + kb];
#pragma unroll
            for (int cf = 0; cf < 4; ++cf) {
                sh8 b = *(const sh8*)(Bt + (size_t)(c0 + cf * 16 + lrow) * KD + kb);
                acc[cf] = __builtin_amdgcn_mfma_f32_16x16x32_bf16(a0, b, acc[cf], 0, 0, 0);
            }
        }

#pragma unroll
        for (int r = 0; r < 4; ++r) {
            int gr = row0 + wv * 16 + lq * 4 + r;
            if (gr >= Crows) continue;
#pragma unroll
            for (int cf = 0; cf < 4; ++cf) {
                int gc = c0 + cf * 16 + lrow;
                float val = acc[cf][r];
                if (gc < SPLIT) {
                    int pi = (gc < PW) ? gc * 2 : (gc - PW) * 2 + 1;
                    Csp[(size_t)gr * SPLIT + pi] = f2bf(val);
                } else if (gc < SPLIT + ROOTW) {
                    Croot[(size_t)gr * ROOTW + (gc - SPLIT)] = val;
                }
            }
        }
    }
}

template <int KD, bool AF32, int SPLIT, int PW, int ROOTW, int MT>
__global__ __launch_bounds__(256) void gemm_mfma(const void* __restrict__ Aptr,
                                                 const unsigned short* __restrict__ Bt,
                                                 unsigned short* __restrict__ Csp,
                                                 float* __restrict__ Croot,
                                                 int Crows) {
    gemm_body<KD, AF32, SPLIT, PW, ROOTW, MT>(blockIdx.x, Aptr, Bt, Csp, Croot, Crows);
}

// ---------------- gather layer 1: one wave/node, static edata addresses ----------------
__global__ __launch_bounds__(256) void gather1(const unsigned short* __restrict__ Ysp,
                                               const float* __restrict__ Yroot,
                                               const int* __restrict__ cnt,
                                               const unsigned int* __restrict__ edata,
                                               const float* __restrict__ bias1,
                                               unsigned short* __restrict__ h) {
    int wave = (blockIdx.x * blockDim.x + threadIdx.x) >> 6;
    int lane = threadIdx.x & 63;
    if (wave >= N_NODES) return;
    int deg = cnt[wave];
    deg = deg > SLOTS ? SLOTS : deg;
    const unsigned int* eb = edata + (size_t)wave * SLOTS;
    const float qs = 1.0f / 65535.0f;
    float acc = 0.0f;
    if (deg <= 16) {
        unsigned int e[16], p[16];
#pragma unroll
        for (int t = 0; t < 16; ++t) e[t] = eb[t];
#pragma unroll
        for (int t = 0; t < 16; ++t) {
            int idx = (t < deg) ? (int)(e[t] & 0xffffu) : 0;
            p[t] = *(const unsigned int*)(Ysp + (size_t)idx * 128 + lane * 2);
        }
#pragma unroll
        for (int t = 0; t < 16; ++t) {
            float m = (t < deg) ? 1.0f : 0.0f;
            float v = (float)(e[t] >> 16) * qs;
            acc += m * ((1.0f - v) * bf2f(p[t] & 0xffffu) + v * bf2f(p[t] >> 16));
        }
    } else {
        unsigned int e[32], p[32];
#pragma unroll
        for (int t = 0; t < 32; ++t) e[t] = eb[t];
#pragma unroll
        for (int t = 0; t < 32; ++t) {
            int idx = (t < deg) ? (int)(e[t] & 0xffffu) : 0;
            p[t] = *(const unsigned int*)(Ysp + (size_t)idx * 128 + lane * 2);
        }
#pragma unroll
        for (int t = 0; t < 32; ++t) {
            float m = (t < deg) ? 1.0f : 0.0f;
            float v = (float)(e[t] >> 16) * qs;
            acc += m * ((1.0f - v) * bf2f(p[t] & 0xffffu) + v * bf2f(p[t] >> 16));
        }
        if (deg > 32) {  // rare
            for (int j = 32; j < deg; j += 8) {
                unsigned int e2[8], p2[8];
#pragma unroll
                for (int t = 0; t < 8; ++t) e2[t] = eb[(j + t < SLOTS) ? (j + t) : 0];
#pragma unroll
                for (int t = 0; t < 8; ++t) {
                    int idx = (j + t < deg) ? (int)(e2[t] & 0xffffu) : 0;
                    p2[t] = *(const unsigned int*)(Ysp + (size_t)idx * 128 + lane * 2);
                }
#pragma unroll
                for (int t = 0; t < 8; ++t) {
                    float m = (j + t < deg) ? 1.0f : 0.0f;
                    float v = (float)(e2[t] >> 16) * qs;
                    acc += m * ((1.0f - v) * bf2f(p2[t] & 0xffffu) + v * bf2f(p2[t] >> 16));
                }
            }
        }
    }
    float dg = (float)deg;
    dg = dg > 1.0f ? dg : 1.0f;
    float m = acc / dg + Yroot[(size_t)wave * HID + lane] + bias1[lane];
    m = m > 0.0f ? m : expm1f(m);  // ELU
    h[(size_t)wave * HID + lane] = f2bf(m);
}

// ---------------- gather layer 2: one wave/node (40 active lanes) ----------------
__global__ __launch_bounds__(256) void gather2(const unsigned short* __restrict__ Zsp,
                                               const float* __restrict__ Zroot,
                                               const int* __restrict__ cnt,
                                               const unsigned int* __restrict__ edata,
                                               const float* __restrict__ bias2,
                                               float* __restrict__ out) {
    int wave = (blockIdx.x * blockDim.x + threadIdx.x) >> 6;
    int lane = threadIdx.x & 63;
    if (wave >= N_NODES) return;
    if (lane >= N_CLS) return;
    int deg = cnt[wave];
    deg = deg > SLOTS ? SLOTS : deg;
    const unsigned int* eb = edata + (size_t)wave * SLOTS;
    const float qs = 1.0f / 65535.0f;
    float acc = 0.0f;
    if (deg <= 16) {
        unsigned int e[16], p[16];
#pragma unroll
        for (int t = 0; t < 16; ++t) e[t] = eb[t];
#pragma unroll
        for (int t = 0; t < 16; ++t) {
            int idx = (t < deg) ? (int)(e[t] & 0xffffu) : 0;
            p[t] = *(const unsigned int*)(Zsp + (size_t)idx * 80 + lane * 2);
        }
#pragma unroll
        for (int t = 0; t < 16; ++t) {
            float m = (t < deg) ? 1.0f : 0.0f;
            float v = (float)(e[t] >> 16) * qs;
            acc += m * ((1.0f - v) * bf2f(p[t] & 0xffffu) + v * bf2f(p[t] >> 16));
        }
    } else {
        unsigned int e[32], p[32];
#pragma unroll
        for (int t = 0; t < 32; ++t) e[t] = eb[t];
#pragma unroll
        for (int t = 0; t < 32; ++t) {
            int idx = (t < deg) ? (int)(e[t] & 0xffffu) : 0;
            p[t] = *(const unsigned int*)(Zsp + (size_t)idx * 80 + lane * 2);
        }
#pragma unroll
        for (int t = 0; t < 32; ++t) {
            float m = (t < deg) ? 1.0f : 0.0f;
            float v = (float)(e[t] >> 16) * qs;
            acc += m * ((1.0f - v) * bf2f(p[t] & 0xffffu) + v * bf2f(p[t] >> 16));
        }
        if (deg > 32) {
            for (int j = 32; j < deg; j += 8) {
                unsigned int e2[8], p2[8];
#pragma unroll
                for (int t = 0; t < 8; ++t) e2[t] = eb[(j + t < SLOTS) ? (j + t) : 0];
#pragma unroll
                for (int t = 0; t < 8; ++t) {
                    int idx = (j + t < deg) ? (int)(e2[t] & 0xffffu) : 0;
                    p2[t] = *(const unsigned int*)(Zsp + (size_t)idx * 80 + lane * 2);
                }
#pragma unroll
                for (int t = 0; t < 8; ++t) {
                    float m = (j + t < deg) ? 1.0f : 0.0f;
                    float v = (float)(e2[t] >> 16) * qs;
                    acc += m * ((1.0f - v) * bf2f(p2[t] & 0xffffu) + v * bf2f(p2[t] >> 16));
                }
            }
        }
    }
    float dg = (float)deg;
    dg = dg > 1.0f ? dg : 1.0f;
    out[(size_t)wave * N_CLS + lane] =
        acc / dg + Zroot[(size_t)wave * N_CLS + lane] + bias2[lane];
}

extern "C" void kernel_launch(void* const* d_in, const int* in_sizes, int n_in,
                              void* d_out, int out_size, void* d_ws, size_t ws_size,
                              hipStream_t stream) {
    const float* x     = (const float*)d_in[0];
    const int*   eidx  = (const int*)d_in[1];
    const float* eattr = (const float*)d_in[2];
    const float* W1    = (const float*)d_in[3];
    const float* root1 = (const float*)d_in[4];
    const float* bias1 = (const float*)d_in[5];
    const float* W2    = (const float*)d_in[6];
    const float* root2 = (const float*)d_in[7];
    const float* bias2 = (const float*)d_in[8];
    float* out = (float*)d_out;

    const int* src = eidx;
    const int* dst = eidx + N_EDGES;

    // workspace layout (bytes)
    char* base = (char*)d_ws;
    unsigned short* Ysp   = (unsigned short*)base;               // 50000*128*2 = 12,800,000
    float*          Yroot = (float*)(base + 12800000);           // 50000*64*4 = 12,800,000
    unsigned short* hb    = (unsigned short*)(base + 25600000);  // 50000*64*2 = 6,400,000
    unsigned short* WT1   = (unsigned short*)(base + 32000000);  // 192*128*2 = 49,152
    unsigned short* WT2   = (unsigned short*)(base + 32049152);  // 128*64*2 = 16,384
    unsigned int*   edata = (unsigned int*)(base + 32065536);    // 50000*40*4 = 8,000,000
    unsigned short* ed16  = (unsigned short*)(base + 40065536);  // 800000*2 = 1,600,000
    unsigned int*   pay32 = (unsigned int*)(base + 41665536);    // 800000*4 = 3,200,000
    int*            cnt   = (int*)(base + 44865536);             // 50,000 ints
    unsigned short* Zsp   = Ysp;                                 // 50000*80*2
    float*          Zroot = Yroot;                               // 50000*40*4

    const int GB = (N_NODES + 63) / 64;  // 782 gemm blocks

    // ---- weights + compressed edge streams ----
    hipLaunchKernelGGL(concat_w, dim3((NW + N_EDGES + 255) / 256), dim3(256), 0, stream,
                       W1, root1, W2, root2, src, dst, eattr, WT1, WT2, ed16, pay32);

    // ---- LDS-staged permute (no global atomics, full-line writes) ----
    hipLaunchKernelGGL(perm_lds, dim3(NRB), dim3(256), 0, stream,
                       ed16, pay32, cnt, edata);

    // ---- layer-1 GEMM ----
    hipLaunchKernelGGL((gemm_mfma<128, true, 128, 64, 64, 3>),
                       dim3(GB), dim3(256), 0, stream,
                       (const void*)x, WT1, Ysp, Yroot, N_NODES);
    hipLaunchKernelGGL(gather1, dim3((N_NODES * 64 + 255) / 256), dim3(256), 0, stream,
                       Ysp, Yroot, cnt, edata, bias1, hb);

    // ---- layer 2 ----
    hipLaunchKernelGGL((gemm_mfma<64, false, 80, 40, 40, 2>),
                       dim3(GB), dim3(256), 0, stream,
                       (const void*)hb, WT2, Zsp, Zroot, N_NODES);
    hipLaunchKernelGGL(gather2, dim3((N_NODES * 64 + 255) / 256), dim3(256), 0, stream,
                       Zsp, Zroot, cnt, edata, bias2, out);
}

// Round 5
// 231.708 us; speedup vs baseline: 2.4553x; 2.4553x over previous
//
#include <hip/hip_runtime.h>
#include <math.h>

#define N_NODES 50000
#define N_EDGES 800000
#define F_IN    128
#define HID     64
#define N_CLS   40

#define M1 (3 * HID)    // 192: [W1_0 | W1_1 | root1]
#define M2P 128         // padded 120: [W2_0 | W2_1 | root2 | 0pad]

#define SLOTS 40        // edata slots per node (max observed deg ~36, Poisson λ=16)
#define NSL 128         // counting-sort slices
#define SLICE_E (N_EDGES / NSL)   // 6250 edges per slice
#define HWORDS (N_NODES / 4)      // 12500 packed-u32 words for a 50000-byte histogram

#define NW 32768        // weight elements in concat_w: M1*F_IN + M2P*HID

using sh8 = __attribute__((ext_vector_type(8))) short;
using floatx4 = __attribute__((ext_vector_type(4))) float;

__device__ inline unsigned short f2bf(float f) {
    union { float f; unsigned int u; } c{f};
    unsigned int r = (c.u + 0x7FFF + ((c.u >> 16) & 1)) >> 16;
    return (unsigned short)r;
}
__device__ inline float bf2f(unsigned int u) {
    union { unsigned int u; float f; } c;
    c.u = u << 16;
    return c.f;
}

// ---------------- weight concat (both layers) + edge payload pack ----------
// pay32[e] = (u16)src[e] | (u16 quantized attr << 16)
__global__ void concat_w(const float* __restrict__ W1, const float* __restrict__ root1,
                         const float* __restrict__ W2, const float* __restrict__ root2,
                         const int* __restrict__ src, const float* __restrict__ attr,
                         unsigned short* __restrict__ WT1, unsigned short* __restrict__ WT2,
                         unsigned int* __restrict__ pay32) {
    int i = blockIdx.x * blockDim.x + threadIdx.x;
    if (i < M1 * F_IN) {
        int c = i / F_IN, k = i % F_IN;
        float val;
        if (c < HID)            val = W1[k * HID + c];
        else if (c < 2 * HID)   val = W1[F_IN * HID + k * HID + (c - HID)];
        else                    val = root1[k * HID + (c - 2 * HID)];
        WT1[i] = f2bf(val);
    } else if (i < NW) {
        int ii = i - M1 * F_IN;
        int c = ii / HID, k = ii % HID;
        float val;
        if (c < N_CLS)            val = W2[k * N_CLS + c];
        else if (c < 2 * N_CLS)   val = W2[HID * N_CLS + k * N_CLS + (c - N_CLS)];
        else if (c < 3 * N_CLS)   val = root2[k * N_CLS + (c - 2 * N_CLS)];
        else                      val = 0.0f;
        WT2[ii] = f2bf(val);
    } else {
        int e = i - NW;
        if (e < N_EDGES) {
            unsigned int q = (unsigned int)(attr[e] * 65535.0f + 0.5f);
            pay32[e] = (unsigned int)src[e] | (q << 16);
        }
    }
}

// ---------------- counting-sort pass 1: per-slice LDS byte histogram ----------
// hist8[s][n] (u8): count of edges in slice s with dst==n. Clean coalesced writes.
__global__ __launch_bounds__(256) void hist_k(const int* __restrict__ dst,
                                              unsigned char* __restrict__ hist8) {
    __shared__ unsigned int h[HWORDS];   // 50 KB packed-u8 counters
    int tid = threadIdx.x, s = blockIdx.x;
    for (int i = tid; i < HWORDS; i += 256) h[i] = 0;
    __syncthreads();
    const int2* dp = (const int2*)(dst + s * SLICE_E);
    for (int i = tid; i < SLICE_E / 2; i += 256) {
        int2 d2 = dp[i];
        atomicAdd(&h[d2.x >> 2], 1u << ((d2.x & 3) * 8));
        atomicAdd(&h[d2.y >> 2], 1u << ((d2.y & 3) * 8));
    }
    __syncthreads();
    unsigned int* out = (unsigned int*)(hist8 + (size_t)s * N_NODES);
    for (int i = tid; i < HWORDS; i += 256) out[i] = h[i];
}

// ---------------- counting-sort pass 2: in-place prefix over slices + cnt ----------
// hist8 becomes offs8 (exclusive prefix per node across slices). cnt[n]=total deg.
__global__ __launch_bounds__(256) void scan_k(unsigned char* __restrict__ hist8,
                                              int* __restrict__ cnt) {
    int n = blockIdx.x * 256 + threadIdx.x;
    if (n >= N_NODES) return;
    int tot = 0;
#pragma unroll 8
    for (int s = 0; s < NSL; ++s) {
        unsigned char c = hist8[(size_t)s * N_NODES + n];
        hist8[(size_t)s * N_NODES + n] = (unsigned char)tot;
        tot += c;
    }
    cnt[n] = tot;
}

// ---------------- counting-sort pass 3: scatter with plain stores ----------
// pos = offs8[s][d] + LDS-rank. Plain 4B stores coalesce in write-back L2
// (only atomics are forced to the memory-side coherence point).
__global__ __launch_bounds__(256) void scatter_k(const int* __restrict__ dst,
                                                 const unsigned int* __restrict__ pay32,
                                                 const unsigned char* __restrict__ offs8,
                                                 unsigned int* __restrict__ edata) {
    __shared__ unsigned int rk[HWORDS];  // 50 KB packed-u8 rank counters
    int tid = threadIdx.x, s = blockIdx.x;
    for (int i = tid; i < HWORDS; i += 256) rk[i] = 0;
    __syncthreads();
    int e0 = s * SLICE_E;
    const unsigned char* ob = offs8 + (size_t)s * N_NODES;
    for (int i = tid; i < SLICE_E; i += 256) {
        int d = dst[e0 + i];
        unsigned int pay = pay32[e0 + i];
        unsigned int old = atomicAdd(&rk[d >> 2], 1u << ((d & 3) * 8));
        int r = (int)((old >> ((d & 3) * 8)) & 0xffu);
        int pos = (int)ob[d] + r;
        if (pos < SLOTS) edata[(size_t)d * SLOTS + pos] = pay;
    }
}

// ---------------- shared gemm body: 64-row tile, A staged in LDS once,
// B fragments read DIRECTLY from global (WT is 16-48 KB, L2-resident).
// No Bs buffer -> 17.4 KB LDS (9 blocks/CU), one barrier total. --------------
template <int KD, bool AF32, int SPLIT, int PW, int ROOTW, int MT>
__device__ __forceinline__ void gemm_body(int bid, const void* __restrict__ Aptr,
                                          const unsigned short* __restrict__ Bt,
                                          unsigned short* __restrict__ Csp,
                                          float* __restrict__ Croot, int Crows) {
    constexpr int KP = KD + 8;
    __shared__ unsigned short As[64 * KP];

    int tid = threadIdx.x;
    int row0 = bid * 64;

    if (AF32) {
        const float* A = (const float*)Aptr;
        for (int c = tid; c < 64 * (KD / 4); c += 256) {
            int r = c / (KD / 4), q = c % (KD / 4);
            int gr = row0 + r;
            float4 v = make_float4(0.f, 0.f, 0.f, 0.f);
            if (gr < Crows) v = *(const float4*)(A + (size_t)gr * KD + q * 4);
            union { unsigned short s[4]; uint2 u; } pk;
            pk.s[0] = f2bf(v.x); pk.s[1] = f2bf(v.y);
            pk.s[2] = f2bf(v.z); pk.s[3] = f2bf(v.w);
            *(uint2*)&As[r * KP + q * 4] = pk.u;
        }
    } else {
        const unsigned short* A = (const unsigned short*)Aptr;
        for (int c = tid; c < 64 * (KD / 8); c += 256) {
            int r = c / (KD / 8), q = c % (KD / 8);
            int gr = row0 + r;
            sh8 v = {};
            if (gr < Crows) v = *(const sh8*)(A + (size_t)gr * KD + q * 8);
            *(sh8*)&As[r * KP + q * 8] = v;
        }
    }
    __syncthreads();  // the ONLY barrier in the kernel

    int wv = tid >> 6, lane = tid & 63;
    int lrow = lane & 15, lq = lane >> 4;

    for (int mt = 0; mt < MT; ++mt) {
        int c0 = mt * 64;

        floatx4 acc[4] = {{0.f,0.f,0.f,0.f},{0.f,0.f,0.f,0.f},{0.f,0.f,0.f,0.f},{0.f,0.f,0.f,0.f}};
#pragma unroll
        for (int kt = 0; kt < KD / 32; ++kt) {
            int kb = kt * 32 + lq * 8;
            sh8 a0 = *(const sh8*)&As[(wv * 16 + lrow) * KP + kb];
#pragma unroll
            for (int cf = 0; cf < 4; ++cf) {
                sh8 b = *(const sh8*)(Bt + (size_t)(c0 + cf * 16 + lrow) * KD + kb);
                acc[cf] = __builtin_amdgcn_mfma_f32_16x16x32_bf16(a0, b, acc[cf], 0, 0, 0);
            }
        }

#pragma unroll
        for (int r = 0; r < 4; ++r) {
            int gr = row0 + wv * 16 + lq * 4 + r;
            if (gr >= Crows) continue;
#pragma unroll
            for (int cf = 0; cf < 4; ++cf) {
                int gc = c0 + cf * 16 + lrow;
                float val = acc[cf][r];
                if (gc < SPLIT) {
                    int pi = (gc < PW) ? gc * 2 : (gc - PW) * 2 + 1;
                    Csp[(size_t)gr * SPLIT + pi] = f2bf(val);
                } else if (gc < SPLIT + ROOTW) {
                    Croot[(size_t)gr * ROOTW + (gc - SPLIT)] = val;
                }
            }
        }
    }
}

template <int KD, bool AF32, int SPLIT, int PW, int ROOTW, int MT>
__global__ __launch_bounds__(256) void gemm_mfma(const void* __restrict__ Aptr,
                                                 const unsigned short* __restrict__ Bt,
                                                 unsigned short* __restrict__ Csp,
                                                 float* __restrict__ Croot,
                                                 int Crows) {
    gemm_body<KD, AF32, SPLIT, PW, ROOTW, MT>(blockIdx.x, Aptr, Bt, Csp, Croot, Crows);
}

// ---------------- gather layer 1: one wave/node, static edata addresses ----------------
__global__ __launch_bounds__(256) void gather1(const unsigned short* __restrict__ Ysp,
                                               const float* __restrict__ Yroot,
                                               const int* __restrict__ cnt,
                                               const unsigned int* __restrict__ edata,
                                               const float* __restrict__ bias1,
                                               unsigned short* __restrict__ h) {
    int wave = (blockIdx.x * blockDim.x + threadIdx.x) >> 6;
    int lane = threadIdx.x & 63;
    if (wave >= N_NODES) return;
    int deg = cnt[wave];
    deg = deg > SLOTS ? SLOTS : deg;
    const unsigned int* eb = edata + (size_t)wave * SLOTS;
    const float qs = 1.0f / 65535.0f;
    float acc = 0.0f;
    if (deg <= 16) {
        unsigned int e[16], p[16];
#pragma unroll
        for (int t = 0; t < 16; ++t) e[t] = eb[t];
#pragma unroll
        for (int t = 0; t < 16; ++t) {
            int idx = (t < deg) ? (int)(e[t] & 0xffffu) : 0;
            p[t] = *(const unsigned int*)(Ysp + (size_t)idx * 128 + lane * 2);
        }
#pragma unroll
        for (int t = 0; t < 16; ++t) {
            float m = (t < deg) ? 1.0f : 0.0f;
            float v = (float)(e[t] >> 16) * qs;
            acc += m * ((1.0f - v) * bf2f(p[t] & 0xffffu) + v * bf2f(p[t] >> 16));
        }
    } else {
        unsigned int e[32], p[32];
#pragma unroll
        for (int t = 0; t < 32; ++t) e[t] = eb[t];
#pragma unroll
        for (int t = 0; t < 32; ++t) {
            int idx = (t < deg) ? (int)(e[t] & 0xffffu) : 0;
            p[t] = *(const unsigned int*)(Ysp + (size_t)idx * 128 + lane * 2);
        }
#pragma unroll
        for (int t = 0; t < 32; ++t) {
            float m = (t < deg) ? 1.0f : 0.0f;
            float v = (float)(e[t] >> 16) * qs;
            acc += m * ((1.0f - v) * bf2f(p[t] & 0xffffu) + v * bf2f(p[t] >> 16));
        }
        if (deg > 32) {  // rare
            for (int j = 32; j < deg; j += 8) {
                unsigned int e2[8], p2[8];
#pragma unroll
                for (int t = 0; t < 8; ++t) e2[t] = eb[(j + t < SLOTS) ? (j + t) : 0];
#pragma unroll
                for (int t = 0; t < 8; ++t) {
                    int idx = (j + t < deg) ? (int)(e2[t] & 0xffffu) : 0;
                    p2[t] = *(const unsigned int*)(Ysp + (size_t)idx * 128 + lane * 2);
                }
#pragma unroll
                for (int t = 0; t < 8; ++t) {
                    float m = (j + t < deg) ? 1.0f : 0.0f;
                    float v = (float)(e2[t] >> 16) * qs;
                    acc += m * ((1.0f - v) * bf2f(p2[t] & 0xffffu) + v * bf2f(p2[t] >> 16));
                }
            }
        }
    }
    float dg = (float)deg;
    dg = dg > 1.0f ? dg : 1.0f;
    float m = acc / dg + Yroot[(size_t)wave * HID + lane] + bias1[lane];
    m = m > 0.0f ? m : expm1f(m);  // ELU
    h[(size_t)wave * HID + lane] = f2bf(m);
}

// ---------------- gather layer 2: one wave/node (40 active lanes) ----------------
__global__ __launch_bounds__(256) void gather2(const unsigned short* __restrict__ Zsp,
                                               const float* __restrict__ Zroot,
                                               const int* __restrict__ cnt,
                                               const unsigned int* __restrict__ edata,
                                               const float* __restrict__ bias2,
                                               float* __restrict__ out) {
    int wave = (blockIdx.x * blockDim.x + threadIdx.x) >> 6;
    int lane = threadIdx.x & 63;
    if (wave >= N_NODES) return;
    if (lane >= N_CLS) return;
    int deg = cnt[wave];
    deg = deg > SLOTS ? SLOTS : deg;
    const unsigned int* eb = edata + (size_t)wave * SLOTS;
    const float qs = 1.0f / 65535.0f;
    float acc = 0.0f;
    if (deg <= 16) {
        unsigned int e[16], p[16];
#pragma unroll
        for (int t = 0; t < 16; ++t) e[t] = eb[t];
#pragma unroll
        for (int t = 0; t < 16; ++t) {
            int idx = (t < deg) ? (int)(e[t] & 0xffffu) : 0;
            p[t] = *(const unsigned int*)(Zsp + (size_t)idx * 80 + lane * 2);
        }
#pragma unroll
        for (int t = 0; t < 16; ++t) {
            float m = (t < deg) ? 1.0f : 0.0f;
            float v = (float)(e[t] >> 16) * qs;
            acc += m * ((1.0f - v) * bf2f(p[t] & 0xffffu) + v * bf2f(p[t] >> 16));
        }
    } else {
        unsigned int e[32], p[32];
#pragma unroll
        for (int t = 0; t < 32; ++t) e[t] = eb[t];
#pragma unroll
        for (int t = 0; t < 32; ++t) {
            int idx = (t < deg) ? (int)(e[t] & 0xffffu) : 0;
            p[t] = *(const unsigned int*)(Zsp + (size_t)idx * 80 + lane * 2);
        }
#pragma unroll
        for (int t = 0; t < 32; ++t) {
            float m = (t < deg) ? 1.0f : 0.0f;
            float v = (float)(e[t] >> 16) * qs;
            acc += m * ((1.0f - v) * bf2f(p[t] & 0xffffu) + v * bf2f(p[t] >> 16));
        }
        if (deg > 32) {
            for (int j = 32; j < deg; j += 8) {
                unsigned int e2[8], p2[8];
#pragma unroll
                for (int t = 0; t < 8; ++t) e2[t] = eb[(j + t < SLOTS) ? (j + t) : 0];
#pragma unroll
                for (int t = 0; t < 8; ++t) {
                    int idx = (j + t < deg) ? (int)(e2[t] & 0xffffu) : 0;
                    p2[t] = *(const unsigned int*)(Zsp + (size_t)idx * 80 + lane * 2);
                }
#pragma unroll
                for (int t = 0; t < 8; ++t) {
                    float m = (j + t < deg) ? 1.0f : 0.0f;
                    float v = (float)(e2[t] >> 16) * qs;
                    acc += m * ((1.0f - v) * bf2f(p2[t] & 0xffffu) + v * bf2f(p2[t] >> 16));
                }
            }
        }
    }
    float dg = (float)deg;
    dg = dg > 1.0f ? dg : 1.0f;
    out[(size_t)wave * N_CLS + lane] =
        acc / dg + Zroot[(size_t)wave * N_CLS + lane] + bias2[lane];
}

extern "C" void kernel_launch(void* const* d_in, const int* in_sizes, int n_in,
                              void* d_out, int out_size, void* d_ws, size_t ws_size,
                              hipStream_t stream) {
    const float* x     = (const float*)d_in[0];
    const int*   eidx  = (const int*)d_in[1];
    const float* eattr = (const float*)d_in[2];
    const float* W1    = (const float*)d_in[3];
    const float* root1 = (const float*)d_in[4];
    const float* bias1 = (const float*)d_in[5];
    const float* W2    = (const float*)d_in[6];
    const float* root2 = (const float*)d_in[7];
    const float* bias2 = (const float*)d_in[8];
    float* out = (float*)d_out;

    const int* src = eidx;
    const int* dst = eidx + N_EDGES;

    // workspace layout (bytes)
    char* base = (char*)d_ws;
    unsigned short* Ysp   = (unsigned short*)base;               // 50000*128*2 = 12,800,000
    float*          Yroot = (float*)(base + 12800000);           // 50000*64*4 = 12,800,000
    unsigned short* hb    = (unsigned short*)(base + 25600000);  // 50000*64*2 = 6,400,000
    unsigned short* WT1   = (unsigned short*)(base + 32000000);  // 192*128*2 = 49,152
    unsigned short* WT2   = (unsigned short*)(base + 32049152);  // 128*64*2 = 16,384
    unsigned int*   edata = (unsigned int*)(base + 32065536);    // 50000*40*4 = 8,000,000
    unsigned int*   pay32 = (unsigned int*)(base + 41665536);    // 800000*4 = 3,200,000
    int*            cnt   = (int*)(base + 44865536);             // 50,000 ints
    // hist/offs scratch reuses the hb region (dead until gather1): 128*50000 = 6,400,000 exact
    unsigned char*  hist8 = (unsigned char*)hb;
    unsigned short* Zsp   = Ysp;                                 // 50000*80*2
    float*          Zroot = Yroot;                               // 50000*40*4

    const int GB = (N_NODES + 63) / 64;  // 782 gemm blocks

    // ---- weights + packed edge payloads ----
    hipLaunchKernelGGL(concat_w, dim3((NW + N_EDGES + 255) / 256), dim3(256), 0, stream,
                       W1, root1, W2, root2, src, eattr, WT1, WT2, pay32);

    // ---- counting-sort permute: hist -> scan -> scatter (no global atomics) ----
    hipLaunchKernelGGL(hist_k, dim3(NSL), dim3(256), 0, stream, dst, hist8);
    hipLaunchKernelGGL(scan_k, dim3((N_NODES + 255) / 256), dim3(256), 0, stream, hist8, cnt);
    hipLaunchKernelGGL(scatter_k, dim3(NSL), dim3(256), 0, stream, dst, pay32, hist8, edata);

    // ---- layer-1 GEMM ----
    hipLaunchKernelGGL((gemm_mfma<128, true, 128, 64, 64, 3>),
                       dim3(GB), dim3(256), 0, stream,
                       (const void*)x, WT1, Ysp, Yroot, N_NODES);
    hipLaunchKernelGGL(gather1, dim3((N_NODES * 64 + 255) / 256), dim3(256), 0, stream,
                       Ysp, Yroot, cnt, edata, bias1, hb);

    // ---- layer 2 ----
    hipLaunchKernelGGL((gemm_mfma<64, false, 80, 40, 40, 2>),
                       dim3(GB), dim3(256), 0, stream,
                       (const void*)hb, WT2, Zsp, Zroot, N_NODES);
    hipLaunchKernelGGL(gather2, dim3((N_NODES * 64 + 255) / 256), dim3(256), 0, stream,
                       Zsp, Zroot, cnt, edata, bias2, out);
}

// Round 6
// 213.003 us; speedup vs baseline: 2.6709x; 1.0878x over previous
//
#include <hip/hip_runtime.h>
#include <math.h>

#define N_NODES 50000
#define N_EDGES 800000
#define F_IN    128
#define HID     64
#define N_CLS   40

#define M1 (3 * HID)    // 192: [W1_0 | W1_1 | root1]
#define M2P 128         // padded 120: [W2_0 | W2_1 | root2 | 0pad], stored k-major [64][128]

#define RANGE_SZ 6250   // 50000 / 8 node ranges (one per XCD)
#define PERM_SLICES 128
#define PERM_CHUNK (N_EDGES / PERM_SLICES)  // 6250
#define EST 64          // edata bucket stride per node (max deg ~36 at lambda=16)

#define NW 32768        // weight elements in concat_w: M1*F_IN + M2P*HID

using sh8 = __attribute__((ext_vector_type(8))) short;
using floatx4 = __attribute__((ext_vector_type(4))) float;

__device__ inline unsigned short f2bf(float f) {
    union { float f; unsigned int u; } c{f};
    unsigned int r = (c.u + 0x7FFF + ((c.u >> 16) & 1)) >> 16;
    return (unsigned short)r;
}
__device__ inline float bf2f(unsigned int u) {
    union { unsigned int u; float f; } c;
    c.u = u << 16;
    return c.f;
}

// ---------------- weight concat (both layers) + cnt zeroing, one launch ----------
// WT1: [192 cols][128 k] col-major-by-col (as before).
// WT2: k-major [k=0..63][c=0..127] so gather1z can stage it coalesced and read
//      lane-consecutive (conflict-free LDS).
__global__ void concat_w(const float* __restrict__ W1, const float* __restrict__ root1,
                         const float* __restrict__ W2, const float* __restrict__ root2,
                         unsigned short* __restrict__ WT1, unsigned short* __restrict__ WT2,
                         int* __restrict__ cnt) {
    int i = blockIdx.x * blockDim.x + threadIdx.x;
    if (i < M1 * F_IN) {
        int c = i / F_IN, k = i % F_IN;
        float val;
        if (c < HID)            val = W1[k * HID + c];
        else if (c < 2 * HID)   val = W1[F_IN * HID + k * HID + (c - HID)];
        else                    val = root1[k * HID + (c - 2 * HID)];
        WT1[i] = f2bf(val);
    } else if (i < NW) {
        int ii = i - M1 * F_IN;
        int k = ii >> 7, c = ii & 127;    // k-major
        float val;
        if (c < N_CLS)            val = W2[k * N_CLS + c];
        else if (c < 2 * N_CLS)   val = W2[HID * N_CLS + k * N_CLS + (c - N_CLS)];
        else if (c < 3 * N_CLS)   val = root2[k * N_CLS + (c - 2 * N_CLS)];
        else                      val = 0.0f;
        WT2[ii] = f2bf(val);
    } else {
        int ii = i - NW;
        if (ii < N_NODES) cnt[ii] = 0;
    }
}

// ---------------- layer-1 gemm body: 64-row tile, A staged once, 3 column tiles ----------
template <int KD, bool AF32, int SPLIT, int PW, int ROOTW, int MT>
__device__ __forceinline__ void gemm_body(int bid, const void* __restrict__ Aptr,
                                          const unsigned short* __restrict__ Bt,
                                          unsigned short* __restrict__ Csp,
                                          float* __restrict__ Croot, int Crows) {
    constexpr int KP = KD + 8;
    __shared__ unsigned short As[64 * KP];
    __shared__ unsigned short Bs[64 * KP];

    int tid = threadIdx.x;
    int row0 = bid * 64;

    if (AF32) {
        const float* A = (const float*)Aptr;
        for (int c = tid; c < 64 * (KD / 4); c += 256) {
            int r = c / (KD / 4), q = c % (KD / 4);
            int gr = row0 + r;
            float4 v = make_float4(0.f, 0.f, 0.f, 0.f);
            if (gr < Crows) v = *(const float4*)(A + (size_t)gr * KD + q * 4);
            union { unsigned short s[4]; uint2 u; } pk;
            pk.s[0] = f2bf(v.x); pk.s[1] = f2bf(v.y);
            pk.s[2] = f2bf(v.z); pk.s[3] = f2bf(v.w);
            *(uint2*)&As[r * KP + q * 4] = pk.u;
        }
    } else {
        const unsigned short* A = (const unsigned short*)Aptr;
        for (int c = tid; c < 64 * (KD / 8); c += 256) {
            int r = c / (KD / 8), q = c % (KD / 8);
            int gr = row0 + r;
            sh8 v = {};
            if (gr < Crows) v = *(const sh8*)(A + (size_t)gr * KD + q * 8);
            *(sh8*)&As[r * KP + q * 8] = v;
        }
    }

    int wv = tid >> 6, lane = tid & 63;
    int lrow = lane & 15, lq = lane >> 4;

    for (int mt = 0; mt < MT; ++mt) {
        int c0 = mt * 64;
        __syncthreads();
        for (int c = tid; c < 64 * (KD / 8); c += 256) {
            int r = c / (KD / 8), q = c % (KD / 8);
            *(sh8*)&Bs[r * KP + q * 8] = *(const sh8*)(Bt + (size_t)(c0 + r) * KD + q * 8);
        }
        __syncthreads();

        floatx4 acc[4] = {{0.f,0.f,0.f,0.f},{0.f,0.f,0.f,0.f},{0.f,0.f,0.f,0.f},{0.f,0.f,0.f,0.f}};
#pragma unroll
        for (int kt = 0; kt < KD / 32; ++kt) {
            int kb = kt * 32 + lq * 8;
            sh8 a0 = *(const sh8*)&As[(wv * 16 + lrow) * KP + kb];
#pragma unroll
            for (int cf = 0; cf < 4; ++cf) {
                sh8 b = *(const sh8*)&Bs[(cf * 16 + lrow) * KP + kb];
                acc[cf] = __builtin_amdgcn_mfma_f32_16x16x32_bf16(a0, b, acc[cf], 0, 0, 0);
            }
        }

#pragma unroll
        for (int r = 0; r < 4; ++r) {
            int gr = row0 + wv * 16 + lq * 4 + r;
            if (gr >= Crows) continue;
#pragma unroll
            for (int cf = 0; cf < 4; ++cf) {
                int gc = c0 + cf * 16 + lrow;
                float val = acc[cf][r];
                if (gc < SPLIT) {
                    int pi = (gc < PW) ? gc * 2 : (gc - PW) * 2 + 1;
                    Csp[(size_t)gr * SPLIT + pi] = f2bf(val);
                } else if (gc < SPLIT + ROOTW) {
                    Croot[(size_t)gr * ROOTW + (gc - SPLIT)] = val;
                }
            }
        }
    }
}

// XCD-range-partitioned bucketed permute: cnt is both histogram and cursor.
// edata[d*EST + pos] — no scan needed. Edge packed 4B: ushort src | ushort attr-fp.
__device__ __forceinline__ void permute_body(int b, const int* __restrict__ src,
                                             const int* __restrict__ dst,
                                             const float* __restrict__ attr,
                                             int* __restrict__ cnt,
                                             unsigned int* __restrict__ edata) {
    int range = b & 7;
    int slice = b >> 3;
    int lo = range * RANGE_SZ;
    int e0 = slice * PERM_CHUNK;
    int e1 = e0 + PERM_CHUNK;
    for (int e = e0 + (int)threadIdx.x; e < e1; e += 256) {
        int d = dst[e];
        if ((unsigned)(d - lo) < (unsigned)RANGE_SZ) {
            int pos = atomicAdd(&cnt[d], 1);
            if (pos < EST) {
                unsigned int q = (unsigned int)(attr[e] * 65535.0f + 0.5f);
                edata[d * EST + pos] = (unsigned int)src[e] | (q << 16);
            }
        }
    }
}

// ---------------- fused layer-1 GEMM + permute (independent work, one launch) ----------
__global__ __launch_bounds__(256) void gemm1_permute(const float* __restrict__ x,
                                                     const unsigned short* __restrict__ WT1,
                                                     unsigned short* __restrict__ Ysp,
                                                     float* __restrict__ Yroot,
                                                     const int* __restrict__ src,
                                                     const int* __restrict__ dst,
                                                     const float* __restrict__ attr,
                                                     int* __restrict__ cnt,
                                                     unsigned int* __restrict__ edata,
                                                     int gemmBlocks) {
    if ((int)blockIdx.x < gemmBlocks) {
        gemm_body<128, true, 128, 64, 64, 3>(blockIdx.x, (const void*)x, WT1, Ysp, Yroot, N_NODES);
    } else {
        permute_body(blockIdx.x - gemmBlocks, src, dst, attr, cnt, edata);
    }
}

// ---------------- gather layer 1 FUSED with layer-2 matvec (gemm2 eliminated) ----------
// One wave per node. After the gather+ELU, lane l holds h[node][l] (f32).
// Broadcast h via LDS (intra-wave exchange, compiler-inserted lgkmcnt; no barrier),
// multiply against LDS-staged k-major W2 (conflict-free lane-consecutive reads),
// write Zsp (packed k0|k1 interleave) + Zroot directly. hb never materialized.
__global__ __launch_bounds__(256) void gather1z(const unsigned short* __restrict__ Ysp,
                                                const float* __restrict__ Yroot,
                                                const int* __restrict__ cnt,
                                                const unsigned int* __restrict__ edata,
                                                const float* __restrict__ bias1,
                                                const unsigned short* __restrict__ WT2,
                                                unsigned short* __restrict__ Zsp,
                                                float* __restrict__ Zroot) {
    __shared__ unsigned short w2s[64 * 128];  // 16 KB, k-major
    __shared__ float hs[4 * 64];              // 1 KB

    int tid = threadIdx.x;
    {   // stage W2 once per block, coalesced uint4
        const uint4* s4 = (const uint4*)WT2;
        uint4* d4 = (uint4*)w2s;
        for (int i = tid; i < (64 * 128) / 8; i += 256) d4[i] = s4[i];
    }
    __syncthreads();

    int wv = tid >> 6, lane = tid & 63;
    int node = blockIdx.x * 4 + wv;
    if (node >= N_NODES) return;

    int deg = cnt[node];
    deg = deg > EST ? EST : deg;
    const unsigned int* eb = edata + (size_t)node * EST;
    const float qs = 1.0f / 65535.0f;
    float acc = 0.0f;
    if (deg <= 16) {
        unsigned int e[16], p[16];
#pragma unroll
        for (int t = 0; t < 16; ++t) e[t] = eb[t];
#pragma unroll
        for (int t = 0; t < 16; ++t) {
            int idx = (t < deg) ? (int)(e[t] & 0xffffu) : 0;
            p[t] = *(const unsigned int*)(Ysp + (size_t)idx * 128 + lane * 2);
        }
#pragma unroll
        for (int t = 0; t < 16; ++t) {
            float m = (t < deg) ? 1.0f : 0.0f;
            float v = (float)(e[t] >> 16) * qs;
            acc += m * ((1.0f - v) * bf2f(p[t] & 0xffffu) + v * bf2f(p[t] >> 16));
        }
    } else {
        unsigned int e[32], p[32];
#pragma unroll
        for (int t = 0; t < 32; ++t) e[t] = eb[t];
#pragma unroll
        for (int t = 0; t < 32; ++t) {
            int idx = (t < deg) ? (int)(e[t] & 0xffffu) : 0;
            p[t] = *(const unsigned int*)(Ysp + (size_t)idx * 128 + lane * 2);
        }
#pragma unroll
        for (int t = 0; t < 32; ++t) {
            float m = (t < deg) ? 1.0f : 0.0f;
            float v = (float)(e[t] >> 16) * qs;
            acc += m * ((1.0f - v) * bf2f(p[t] & 0xffffu) + v * bf2f(p[t] >> 16));
        }
        if (deg > 32) {  // rare (P ~ 1e-4 per node)
            for (int j = 32; j < deg; j += 8) {
                unsigned int e2[8], p2[8];
#pragma unroll
                for (int t = 0; t < 8; ++t) e2[t] = eb[j + t];
#pragma unroll
                for (int t = 0; t < 8; ++t) {
                    int idx = (j + t < deg) ? (int)(e2[t] & 0xffffu) : 0;
                    p2[t] = *(const unsigned int*)(Ysp + (size_t)idx * 128 + lane * 2);
                }
#pragma unroll
                for (int t = 0; t < 8; ++t) {
                    float m = (j + t < deg) ? 1.0f : 0.0f;
                    float v = (float)(e2[t] >> 16) * qs;
                    acc += m * ((1.0f - v) * bf2f(p2[t] & 0xffffu) + v * bf2f(p2[t] >> 16));
                }
            }
        }
    }
    float dg = (float)deg;
    dg = dg > 1.0f ? dg : 1.0f;
    float m = acc / dg + Yroot[(size_t)node * HID + lane] + bias1[lane];
    m = m > 0.0f ? m : expm1f(m);  // ELU -> h[node][lane], f32 (more precise than old bf16 hb)

    hs[wv * 64 + lane] = m;
    // intra-wave LDS write->read: compiler emits lgkmcnt wait; wave64 lockstep, no barrier

    float z0 = 0.0f, z1 = 0.0f;   // output cols c0=lane, c1=lane+64 of [W2_0|W2_1|root2|pad]
#pragma unroll 16
    for (int k = 0; k < 64; ++k) {
        float hk = hs[wv * 64 + k];                 // LDS broadcast (uniform addr)
        z0 += hk * bf2f(w2s[k * 128 + lane]);       // lane-consecutive: conflict-free
        z1 += hk * bf2f(w2s[k * 128 + 64 + lane]);
    }

    // epilogue: same split layout gemm2 produced (Zsp interleaved pairs, Zroot f32)
    {   // c0 = lane in [0,64): always in the Zsp split region (<80)
        int pi = (lane < N_CLS) ? lane * 2 : (lane - N_CLS) * 2 + 1;
        Zsp[(size_t)node * 80 + pi] = f2bf(z0);
    }
    int c1 = lane + 64;
    if (c1 < 80) {
        int pi = (c1 - N_CLS) * 2 + 1;
        Zsp[(size_t)node * 80 + pi] = f2bf(z1);
    } else if (c1 < 120) {
        Zroot[(size_t)node * N_CLS + (c1 - 80)] = z1;
    }   // c1 >= 120: padding, discard
}

// ---------------- gather layer 2: one wave/node (40 active lanes) ----------------
__global__ __launch_bounds__(256) void gather2(const unsigned short* __restrict__ Zsp,
                                               const float* __restrict__ Zroot,
                                               const int* __restrict__ cnt,
                                               const unsigned int* __restrict__ edata,
                                               const float* __restrict__ bias2,
                                               float* __restrict__ out) {
    int wave = (blockIdx.x * blockDim.x + threadIdx.x) >> 6;
    int lane = threadIdx.x & 63;
    if (wave >= N_NODES) return;
    if (lane >= N_CLS) return;
    int deg = cnt[wave];
    deg = deg > EST ? EST : deg;
    const unsigned int* eb = edata + (size_t)wave * EST;
    const float qs = 1.0f / 65535.0f;
    float acc = 0.0f;
    if (deg <= 16) {
        unsigned int e[16], p[16];
#pragma unroll
        for (int t = 0; t < 16; ++t) e[t] = eb[t];
#pragma unroll
        for (int t = 0; t < 16; ++t) {
            int idx = (t < deg) ? (int)(e[t] & 0xffffu) : 0;
            p[t] = *(const unsigned int*)(Zsp + (size_t)idx * 80 + lane * 2);
        }
#pragma unroll
        for (int t = 0; t < 16; ++t) {
            float m = (t < deg) ? 1.0f : 0.0f;
            float v = (float)(e[t] >> 16) * qs;
            acc += m * ((1.0f - v) * bf2f(p[t] & 0xffffu) + v * bf2f(p[t] >> 16));
        }
    } else {
        unsigned int e[32], p[32];
#pragma unroll
        for (int t = 0; t < 32; ++t) e[t] = eb[t];
#pragma unroll
        for (int t = 0; t < 32; ++t) {
            int idx = (t < deg) ? (int)(e[t] & 0xffffu) : 0;
            p[t] = *(const unsigned int*)(Zsp + (size_t)idx * 80 + lane * 2);
        }
#pragma unroll
        for (int t = 0; t < 32; ++t) {
            float m = (t < deg) ? 1.0f : 0.0f;
            float v = (float)(e[t] >> 16) * qs;
            acc += m * ((1.0f - v) * bf2f(p[t] & 0xffffu) + v * bf2f(p[t] >> 16));
        }
        if (deg > 32) {
            for (int j = 32; j < deg; j += 8) {
                unsigned int e2[8], p2[8];
#pragma unroll
                for (int t = 0; t < 8; ++t) e2[t] = eb[j + t];
#pragma unroll
                for (int t = 0; t < 8; ++t) {
                    int idx = (j + t < deg) ? (int)(e2[t] & 0xffffu) : 0;
                    p2[t] = *(const unsigned int*)(Zsp + (size_t)idx * 80 + lane * 2);
                }
#pragma unroll
                for (int t = 0; t < 8; ++t) {
                    float m = (j + t < deg) ? 1.0f : 0.0f;
                    float v = (float)(e2[t] >> 16) * qs;
                    acc += m * ((1.0f - v) * bf2f(p2[t] & 0xffffu) + v * bf2f(p2[t] >> 16));
                }
            }
        }
    }
    float dg = (float)deg;
    dg = dg > 1.0f ? dg : 1.0f;
    out[(size_t)wave * N_CLS + lane] =
        acc / dg + Zroot[(size_t)wave * N_CLS + lane] + bias2[lane];
}

extern "C" void kernel_launch(void* const* d_in, const int* in_sizes, int n_in,
                              void* d_out, int out_size, void* d_ws, size_t ws_size,
                              hipStream_t stream) {
    const float* x     = (const float*)d_in[0];
    const int*   eidx  = (const int*)d_in[1];
    const float* eattr = (const float*)d_in[2];
    const float* W1    = (const float*)d_in[3];
    const float* root1 = (const float*)d_in[4];
    const float* bias1 = (const float*)d_in[5];
    const float* W2    = (const float*)d_in[6];
    const float* root2 = (const float*)d_in[7];
    const float* bias2 = (const float*)d_in[8];
    float* out = (float*)d_out;

    const int* src = eidx;
    const int* dst = eidx + N_EDGES;

    // workspace layout (bytes)
    char* base = (char*)d_ws;
    unsigned short* Ysp   = (unsigned short*)base;               // 50000*128*2 = 12,800,000
    float*          Yroot = (float*)(base + 12800000);           // 50000*64*4 = 12,800,000
    // [25,600,000 .. 32,000,000) free (old hb slot)
    unsigned short* WT1   = (unsigned short*)(base + 32000000);  // 192*128*2 = 49,152
    unsigned short* WT2   = (unsigned short*)(base + 32049152);  // 64*128*2 = 16,384 (k-major)
    unsigned int*   edata = (unsigned int*)(base + 32065536);    // 50000*64*4 = 12,800,000
    int*            cnt   = (int*)(base + 44865536);             // 50,000*4 = 200,000
    unsigned short* Zsp   = (unsigned short*)(base + 45065536);  // 50000*80*2 = 8,000,000 (no alias!)
    float*          Zroot = (float*)(base + 53065536);           // 50000*40*4 = 8,000,000

    const int GB = (N_NODES + 63) / 64;  // 782 gemm blocks

    // ---- weights (WT2 transposed k-major) + cnt zeroing ----
    hipLaunchKernelGGL(concat_w, dim3((NW + N_NODES + 255) / 256), dim3(256), 0, stream,
                       W1, root1, W2, root2, WT1, WT2, cnt);

    // ---- layer-1 GEMM fused with bucketed permute (round-0 structure) ----
    hipLaunchKernelGGL(gemm1_permute, dim3(GB + 8 * PERM_SLICES), dim3(256), 0, stream,
                       x, WT1, Ysp, Yroot, src, dst, eattr, cnt, edata, GB);

    // ---- gather1 + fused layer-2 matvec (gemm2 launch eliminated) ----
    hipLaunchKernelGGL(gather1z, dim3((N_NODES + 3) / 4), dim3(256), 0, stream,
                       Ysp, Yroot, cnt, edata, bias1, WT2, Zsp, Zroot);

    // ---- layer-2 gather ----
    hipLaunchKernelGGL(gather2, dim3((N_NODES * 64 + 255) / 256), dim3(256), 0, stream,
                       Zsp, Zroot, cnt, edata, bias2, out);
}

// Round 7
// 200.366 us; speedup vs baseline: 2.8393x; 1.0631x over previous
//
#include <hip/hip_runtime.h>
#include <math.h>

#define N_NODES 50000
#define N_EDGES 800000
#define F_IN    128
#define HID     64
#define N_CLS   40

#define M1 (3 * HID)    // 192: [W1_0 | W1_1 | root1]
#define M2P 128         // padded 120: [W2_0 | W2_1 | root2 | 0pad]

#define RANGE_SZ 6250   // 50000 / 8 node ranges (one per XCD)
#define PERM_SLICES 128
#define PERM_CHUNK (N_EDGES / PERM_SLICES)  // 6250
#define EST 64          // edata bucket stride per node (max deg ~36 at lambda=16)

#define NW 32768        // weight elements in concat_w: M1*F_IN + M2P*HID

using sh8 = __attribute__((ext_vector_type(8))) short;
using floatx4 = __attribute__((ext_vector_type(4))) float;

__device__ inline unsigned short f2bf(float f) {
    union { float f; unsigned int u; } c{f};
    unsigned int r = (c.u + 0x7FFF + ((c.u >> 16) & 1)) >> 16;
    return (unsigned short)r;
}
__device__ inline float bf2f(unsigned int u) {
    union { unsigned int u; float f; } c;
    c.u = u << 16;
    return c.f;
}

// ---------------- weight concat (both layers) + cnt zeroing, one launch ----------
__global__ void concat_w(const float* __restrict__ W1, const float* __restrict__ root1,
                         const float* __restrict__ W2, const float* __restrict__ root2,
                         unsigned short* __restrict__ WT1, unsigned short* __restrict__ WT2,
                         int* __restrict__ cnt) {
    int i = blockIdx.x * blockDim.x + threadIdx.x;
    if (i < M1 * F_IN) {
        int c = i / F_IN, k = i % F_IN;
        float val;
        if (c < HID)            val = W1[k * HID + c];
        else if (c < 2 * HID)   val = W1[F_IN * HID + k * HID + (c - HID)];
        else                    val = root1[k * HID + (c - 2 * HID)];
        WT1[i] = f2bf(val);
    } else if (i < NW) {
        int ii = i - M1 * F_IN;
        int c = ii / HID, k = ii % HID;
        float val;
        if (c < N_CLS)            val = W2[k * N_CLS + c];
        else if (c < 2 * N_CLS)   val = W2[HID * N_CLS + k * N_CLS + (c - N_CLS)];
        else if (c < 3 * N_CLS)   val = root2[k * N_CLS + (c - 2 * N_CLS)];
        else                      val = 0.0f;
        WT2[ii] = f2bf(val);
    } else {
        int ii = i - NW;
        if (ii < N_NODES) cnt[ii] = 0;
    }
}

// ---------------- shared gemm body: 64-row tile, A staged once, MT column tiles ----------
template <int KD, bool AF32, int SPLIT, int PW, int ROOTW, int MT>
__device__ __forceinline__ void gemm_body(int bid, const void* __restrict__ Aptr,
                                          const unsigned short* __restrict__ Bt,
                                          unsigned short* __restrict__ Csp,
                                          float* __restrict__ Croot, int Crows) {
    constexpr int KP = KD + 8;
    __shared__ unsigned short As[64 * KP];
    __shared__ unsigned short Bs[64 * KP];

    int tid = threadIdx.x;
    int row0 = bid * 64;

    if (AF32) {
        const float* A = (const float*)Aptr;
        for (int c = tid; c < 64 * (KD / 4); c += 256) {
            int r = c / (KD / 4), q = c % (KD / 4);
            int gr = row0 + r;
            float4 v = make_float4(0.f, 0.f, 0.f, 0.f);
            if (gr < Crows) v = *(const float4*)(A + (size_t)gr * KD + q * 4);
            union { unsigned short s[4]; uint2 u; } pk;
            pk.s[0] = f2bf(v.x); pk.s[1] = f2bf(v.y);
            pk.s[2] = f2bf(v.z); pk.s[3] = f2bf(v.w);
            *(uint2*)&As[r * KP + q * 4] = pk.u;
        }
    } else {
        const unsigned short* A = (const unsigned short*)Aptr;
        for (int c = tid; c < 64 * (KD / 8); c += 256) {
            int r = c / (KD / 8), q = c % (KD / 8);
            int gr = row0 + r;
            sh8 v = {};
            if (gr < Crows) v = *(const sh8*)(A + (size_t)gr * KD + q * 8);
            *(sh8*)&As[r * KP + q * 8] = v;
        }
    }

    int wv = tid >> 6, lane = tid & 63;
    int lrow = lane & 15, lq = lane >> 4;

    for (int mt = 0; mt < MT; ++mt) {
        int c0 = mt * 64;
        __syncthreads();
        for (int c = tid; c < 64 * (KD / 8); c += 256) {
            int r = c / (KD / 8), q = c % (KD / 8);
            *(sh8*)&Bs[r * KP + q * 8] = *(const sh8*)(Bt + (size_t)(c0 + r) * KD + q * 8);
        }
        __syncthreads();

        floatx4 acc[4] = {{0.f,0.f,0.f,0.f},{0.f,0.f,0.f,0.f},{0.f,0.f,0.f,0.f},{0.f,0.f,0.f,0.f}};
#pragma unroll
        for (int kt = 0; kt < KD / 32; ++kt) {
            int kb = kt * 32 + lq * 8;
            sh8 a0 = *(const sh8*)&As[(wv * 16 + lrow) * KP + kb];
#pragma unroll
            for (int cf = 0; cf < 4; ++cf) {
                sh8 b = *(const sh8*)&Bs[(cf * 16 + lrow) * KP + kb];
                acc[cf] = __builtin_amdgcn_mfma_f32_16x16x32_bf16(a0, b, acc[cf], 0, 0, 0);
            }
        }

#pragma unroll
        for (int r = 0; r < 4; ++r) {
            int gr = row0 + wv * 16 + lq * 4 + r;
            if (gr >= Crows) continue;
#pragma unroll
            for (int cf = 0; cf < 4; ++cf) {
                int gc = c0 + cf * 16 + lrow;
                float val = acc[cf][r];
                if (gc < SPLIT) {
                    int pi = (gc < PW) ? gc * 2 : (gc - PW) * 2 + 1;
                    Csp[(size_t)gr * SPLIT + pi] = f2bf(val);
                } else if (gc < SPLIT + ROOTW) {
                    Croot[(size_t)gr * ROOTW + (gc - SPLIT)] = val;
                }
            }
        }
    }
}

// XCD-range-partitioned bucketed permute: cnt is both histogram and cursor.
__device__ __forceinline__ void permute_body(int b, const int* __restrict__ src,
                                             const int* __restrict__ dst,
                                             const float* __restrict__ attr,
                                             int* __restrict__ cnt,
                                             unsigned int* __restrict__ edata) {
    int range = b & 7;
    int slice = b >> 3;
    int lo = range * RANGE_SZ;
    int e0 = slice * PERM_CHUNK;
    int e1 = e0 + PERM_CHUNK;
    for (int e = e0 + (int)threadIdx.x; e < e1; e += 256) {
        int d = dst[e];
        if ((unsigned)(d - lo) < (unsigned)RANGE_SZ) {
            int pos = atomicAdd(&cnt[d], 1);
            if (pos < EST) {
                unsigned int q = (unsigned int)(attr[e] * 65535.0f + 0.5f);
                edata[d * EST + pos] = (unsigned int)src[e] | (q << 16);
            }
        }
    }
}

// ---------------- fused layer-1 GEMM + permute (independent work, one launch) ----------
__global__ __launch_bounds__(256) void gemm1_permute(const float* __restrict__ x,
                                                     const unsigned short* __restrict__ WT1,
                                                     unsigned short* __restrict__ Ysp,
                                                     float* __restrict__ Yroot,
                                                     const int* __restrict__ src,
                                                     const int* __restrict__ dst,
                                                     const float* __restrict__ attr,
                                                     int* __restrict__ cnt,
                                                     unsigned int* __restrict__ edata,
                                                     int gemmBlocks) {
    if ((int)blockIdx.x < gemmBlocks) {
        gemm_body<128, true, 128, 64, 64, 3>(blockIdx.x, (const void*)x, WT1, Ysp, Yroot, N_NODES);
    } else {
        permute_body(blockIdx.x - gemmBlocks, src, dst, attr, cnt, edata);
    }
}

// ---------------- standalone layer-2 GEMM ----------
template <int KD, bool AF32, int SPLIT, int PW, int ROOTW, int MT>
__global__ __launch_bounds__(256) void gemm_mfma(const void* __restrict__ Aptr,
                                                 const unsigned short* __restrict__ Bt,
                                                 unsigned short* __restrict__ Csp,
                                                 float* __restrict__ Croot,
                                                 int Crows) {
    gemm_body<KD, AF32, SPLIT, PW, ROOTW, MT>(blockIdx.x, Aptr, Bt, Csp, Croot, Crows);
}

// ---------------- gather layer 1: one wave/node, HALF-WAVE EDGE PAIRING ----------
// lane = (stream h = lane>>5, feature-pair c = lane&31). Each half-wave handles
// alternate edges with 8B uint2 loads (features 2c,2c+1 packed pairs) — same
// bytes as before, HALF the vector-load instructions. Cross-half combine via
// 2x shfl_xor(.,32).
__global__ __launch_bounds__(256) void gather1(const unsigned short* __restrict__ Ysp,
                                               const float* __restrict__ Yroot,
                                               const int* __restrict__ cnt,
                                               const unsigned int* __restrict__ edata,
                                               const float* __restrict__ bias1,
                                               unsigned short* __restrict__ h) {
    int wave = (blockIdx.x * blockDim.x + threadIdx.x) >> 6;
    int lane = threadIdx.x & 63;
    if (wave >= N_NODES) return;
    int hf = lane >> 5;       // edge stream (0: even edges, 1: odd edges)
    int c  = lane & 31;       // feature pair -> features 2c, 2c+1
    int deg = cnt[wave];
    deg = deg > EST ? EST : deg;
    const unsigned int* eb = edata + (size_t)wave * EST;
    const float qs = 1.0f / 65535.0f;
    float a0 = 0.0f, a1 = 0.0f;
    if (deg <= 16) {
        unsigned int e[8]; uint2 p[8];
#pragma unroll
        for (int t = 0; t < 8; ++t) e[t] = eb[2 * t + hf];
#pragma unroll
        for (int t = 0; t < 8; ++t) {
            int idx = (2 * t + hf < deg) ? (int)(e[t] & 0xffffu) : 0;
            p[t] = *(const uint2*)(Ysp + (size_t)idx * 128 + c * 4);
        }
#pragma unroll
        for (int t = 0; t < 8; ++t) {
            float m = (2 * t + hf < deg) ? 1.0f : 0.0f;
            float v = (float)(e[t] >> 16) * qs;
            float w = 1.0f - v;
            a0 += m * (w * bf2f(p[t].x & 0xffffu) + v * bf2f(p[t].x >> 16));
            a1 += m * (w * bf2f(p[t].y & 0xffffu) + v * bf2f(p[t].y >> 16));
        }
    } else {
        unsigned int e[16]; uint2 p[16];
#pragma unroll
        for (int t = 0; t < 16; ++t) e[t] = eb[2 * t + hf];
#pragma unroll
        for (int t = 0; t < 16; ++t) {
            int idx = (2 * t + hf < deg) ? (int)(e[t] & 0xffffu) : 0;
            p[t] = *(const uint2*)(Ysp + (size_t)idx * 128 + c * 4);
        }
#pragma unroll
        for (int t = 0; t < 16; ++t) {
            float m = (2 * t + hf < deg) ? 1.0f : 0.0f;
            float v = (float)(e[t] >> 16) * qs;
            float w = 1.0f - v;
            a0 += m * (w * bf2f(p[t].x & 0xffffu) + v * bf2f(p[t].x >> 16));
            a1 += m * (w * bf2f(p[t].y & 0xffffu) + v * bf2f(p[t].y >> 16));
        }
        if (deg > 32) {  // rare (P ~ 1e-4 per node)
            for (int j = 32 + hf; j < deg; j += 2) {
                unsigned int ee = eb[j];
                int idx = (int)(ee & 0xffffu);
                uint2 pp = *(const uint2*)(Ysp + (size_t)idx * 128 + c * 4);
                float v = (float)(ee >> 16) * qs;
                float w = 1.0f - v;
                a0 += w * bf2f(pp.x & 0xffffu) + v * bf2f(pp.x >> 16);
                a1 += w * bf2f(pp.y & 0xffffu) + v * bf2f(pp.y >> 16);
            }
        }
    }
    a0 += __shfl_xor(a0, 32);
    a1 += __shfl_xor(a1, 32);
    float dg = (float)deg;
    dg = dg > 1.0f ? dg : 1.0f;
    float2 yr = *(const float2*)(Yroot + (size_t)wave * HID + c * 2);
    float2 bi = *(const float2*)(bias1 + c * 2);
    float m0 = a0 / dg + yr.x + bi.x;
    float m1 = a1 / dg + yr.y + bi.y;
    m0 = m0 > 0.0f ? m0 : expm1f(m0);  // ELU
    m1 = m1 > 0.0f ? m1 : expm1f(m1);
    if (hf == 0) {
        unsigned int u = (unsigned int)f2bf(m0) | ((unsigned int)f2bf(m1) << 16);
        *(unsigned int*)(h + (size_t)wave * HID + c * 2) = u;
    }
}

// ---------------- gather layer 2: half-wave edge pairing, class pairs (c<20) ----------
__global__ __launch_bounds__(256) void gather2(const unsigned short* __restrict__ Zsp,
                                               const float* __restrict__ Zroot,
                                               const int* __restrict__ cnt,
                                               const unsigned int* __restrict__ edata,
                                               const float* __restrict__ bias2,
                                               float* __restrict__ out) {
    int wave = (blockIdx.x * blockDim.x + threadIdx.x) >> 6;
    int lane = threadIdx.x & 63;
    if (wave >= N_NODES) return;
    int hf = lane >> 5;
    int c  = lane & 31;       // class pair -> classes 2c, 2c+1 (active: c<20)
    int deg = cnt[wave];
    deg = deg > EST ? EST : deg;
    const unsigned int* eb = edata + (size_t)wave * EST;
    const float qs = 1.0f / 65535.0f;
    float a0 = 0.0f, a1 = 0.0f;
    if (c < 20) {
        if (deg <= 16) {
            unsigned int e[8]; uint2 p[8];
#pragma unroll
            for (int t = 0; t < 8; ++t) e[t] = eb[2 * t + hf];
#pragma unroll
            for (int t = 0; t < 8; ++t) {
                int idx = (2 * t + hf < deg) ? (int)(e[t] & 0xffffu) : 0;
                p[t] = *(const uint2*)(Zsp + (size_t)idx * 80 + c * 4);
            }
#pragma unroll
            for (int t = 0; t < 8; ++t) {
                float m = (2 * t + hf < deg) ? 1.0f : 0.0f;
                float v = (float)(e[t] >> 16) * qs;
                float w = 1.0f - v;
                a0 += m * (w * bf2f(p[t].x & 0xffffu) + v * bf2f(p[t].x >> 16));
                a1 += m * (w * bf2f(p[t].y & 0xffffu) + v * bf2f(p[t].y >> 16));
            }
        } else {
            unsigned int e[16]; uint2 p[16];
#pragma unroll
            for (int t = 0; t < 16; ++t) e[t] = eb[2 * t + hf];
#pragma unroll
            for (int t = 0; t < 16; ++t) {
                int idx = (2 * t + hf < deg) ? (int)(e[t] & 0xffffu) : 0;
                p[t] = *(const uint2*)(Zsp + (size_t)idx * 80 + c * 4);
            }
#pragma unroll
            for (int t = 0; t < 16; ++t) {
                float m = (2 * t + hf < deg) ? 1.0f : 0.0f;
                float v = (float)(e[t] >> 16) * qs;
                float w = 1.0f - v;
                a0 += m * (w * bf2f(p[t].x & 0xffffu) + v * bf2f(p[t].x >> 16));
                a1 += m * (w * bf2f(p[t].y & 0xffffu) + v * bf2f(p[t].y >> 16));
            }
            if (deg > 32) {
                for (int j = 32 + hf; j < deg; j += 2) {
                    unsigned int ee = eb[j];
                    int idx = (int)(ee & 0xffffu);
                    uint2 pp = *(const uint2*)(Zsp + (size_t)idx * 80 + c * 4);
                    float v = (float)(ee >> 16) * qs;
                    float w = 1.0f - v;
                    a0 += w * bf2f(pp.x & 0xffffu) + v * bf2f(pp.x >> 16);
                    a1 += w * bf2f(pp.y & 0xffffu) + v * bf2f(pp.y >> 16);
                }
            }
        }
    }
    a0 += __shfl_xor(a0, 32);
    a1 += __shfl_xor(a1, 32);
    if (hf == 0 && c < 20) {
        float dg = (float)deg;
        dg = dg > 1.0f ? dg : 1.0f;
        float2 zr = *(const float2*)(Zroot + (size_t)wave * N_CLS + c * 2);
        float2 bi = *(const float2*)(bias2 + c * 2);
        float2 o;
        o.x = a0 / dg + zr.x + bi.x;
        o.y = a1 / dg + zr.y + bi.y;
        *(float2*)(out + (size_t)wave * N_CLS + c * 2) = o;
    }
}

extern "C" void kernel_launch(void* const* d_in, const int* in_sizes, int n_in,
                              void* d_out, int out_size, void* d_ws, size_t ws_size,
                              hipStream_t stream) {
    const float* x     = (const float*)d_in[0];
    const int*   eidx  = (const int*)d_in[1];
    const float* eattr = (const float*)d_in[2];
    const float* W1    = (const float*)d_in[3];
    const float* root1 = (const float*)d_in[4];
    const float* bias1 = (const float*)d_in[5];
    const float* W2    = (const float*)d_in[6];
    const float* root2 = (const float*)d_in[7];
    const float* bias2 = (const float*)d_in[8];
    float* out = (float*)d_out;

    const int* src = eidx;
    const int* dst = eidx + N_EDGES;

    // workspace layout (bytes) — round-0 proven layout
    char* base = (char*)d_ws;
    unsigned short* Ysp   = (unsigned short*)base;               // 50000*128*2 = 12,800,000
    float*          Yroot = (float*)(base + 12800000);           // 50000*64*4 = 12,800,000
    unsigned short* hb    = (unsigned short*)(base + 25600000);  // 50000*64*2 = 6,400,000
    unsigned short* WT1   = (unsigned short*)(base + 32000000);  // 192*128*2 = 49,152
    unsigned short* WT2   = (unsigned short*)(base + 32049152);  // 128*64*2 = 16,384
    unsigned int*   edata = (unsigned int*)(base + 32065536);    // 50000*64*4 = 12,800,000
    int*            cnt   = (int*)(base + 44865536);             // 50,000 ints
    unsigned short* Zsp   = Ysp;                                 // 50000*80*2
    float*          Zroot = Yroot;                               // 50000*40*4

    const int GB = (N_NODES + 63) / 64;  // 782 gemm blocks

    // ---- weights + cnt zeroing ----
    hipLaunchKernelGGL(concat_w, dim3((NW + N_NODES + 255) / 256), dim3(256), 0, stream,
                       W1, root1, W2, root2, WT1, WT2, cnt);

    // ---- layer-1 GEMM fused with bucketed permute ----
    hipLaunchKernelGGL(gemm1_permute, dim3(GB + 8 * PERM_SLICES), dim3(256), 0, stream,
                       x, WT1, Ysp, Yroot, src, dst, eattr, cnt, edata, GB);
    hipLaunchKernelGGL(gather1, dim3((N_NODES * 64 + 255) / 256), dim3(256), 0, stream,
                       Ysp, Yroot, cnt, edata, bias1, hb);

    // ---- layer 2 ----
    hipLaunchKernelGGL((gemm_mfma<64, false, 80, 40, 40, 2>),
                       dim3(GB), dim3(256), 0, stream,
                       (const void*)hb, WT2, Zsp, Zroot, N_NODES);
    hipLaunchKernelGGL(gather2, dim3((N_NODES * 64 + 255) / 256), dim3(256), 0, stream,
                       Zsp, Zroot, cnt, edata, bias2, out);
}

// Round 8
// 198.238 us; speedup vs baseline: 2.8698x; 1.0107x over previous
//
#include <hip/hip_runtime.h>
#include <math.h>

#define N_NODES 50000
#define N_EDGES 800000
#define F_IN    128
#define HID     64
#define N_CLS   40

#define M1 (3 * HID)    // 192: [W1_0 | W1_1 | root1]
#define K2  192         // layer-2 GEMM depth: [agg0(64) | agg1(64) | h(64)]

#define RANGE_SZ 6250   // 50000 / 8 node ranges (one per XCD)
#define PERM_SLICES 128
#define PERM_CHUNK (N_EDGES / PERM_SLICES)  // 6250
#define EST 64          // edata bucket stride per node (max deg ~36 at lambda=16)

#define NW (M1 * F_IN + N_CLS * K2)   // 24576 + 7680 = 32256 weight elements

using sh8 = __attribute__((ext_vector_type(8))) short;
using floatx4 = __attribute__((ext_vector_type(4))) float;

__device__ inline unsigned short f2bf(float f) {
    union { float f; unsigned int u; } c{f};
    unsigned int r = (c.u + 0x7FFF + ((c.u >> 16) & 1)) >> 16;
    return (unsigned short)r;
}
__device__ inline float bf2f(unsigned int u) {
    union { unsigned int u; float f; } c;
    c.u = u << 16;
    return c.f;
}

// ---------------- weight concat (both layers) + cnt zeroing, one launch ----------
// WT1: [192 cols][128 k], k contiguous (unchanged).
// WT2: [40 cols][192 k], k contiguous: k<64 -> W2_0[k][c]; 64..127 -> W2_1; 128..191 -> root2.
__global__ void concat_w(const float* __restrict__ W1, const float* __restrict__ root1,
                         const float* __restrict__ W2, const float* __restrict__ root2,
                         unsigned short* __restrict__ WT1, unsigned short* __restrict__ WT2,
                         int* __restrict__ cnt) {
    int i = blockIdx.x * blockDim.x + threadIdx.x;
    if (i < M1 * F_IN) {
        int c = i / F_IN, k = i % F_IN;
        float val;
        if (c < HID)            val = W1[k * HID + c];
        else if (c < 2 * HID)   val = W1[F_IN * HID + k * HID + (c - HID)];
        else                    val = root1[k * HID + (c - 2 * HID)];
        WT1[i] = f2bf(val);
    } else if (i < NW) {
        int ii = i - M1 * F_IN;          // ii = c*192 + k
        int c = ii / K2, k = ii % K2;
        float val;
        if (k < HID)             val = W2[k * N_CLS + c];
        else if (k < 2 * HID)    val = W2[HID * N_CLS + (k - HID) * N_CLS + c];
        else                     val = root2[(k - 2 * HID) * N_CLS + c];
        WT2[ii] = f2bf(val);
    } else {
        int ii = i - NW;
        if (ii < N_NODES) cnt[ii] = 0;
    }
}

// ---------------- layer-1 gemm body: 64-row tile, A staged once, 3 column tiles ----------
template <int KD, bool AF32, int SPLIT, int PW, int ROOTW, int MT>
__device__ __forceinline__ void gemm_body(int bid, const void* __restrict__ Aptr,
                                          const unsigned short* __restrict__ Bt,
                                          unsigned short* __restrict__ Csp,
                                          float* __restrict__ Croot, int Crows) {
    constexpr int KP = KD + 8;
    __shared__ unsigned short As[64 * KP];
    __shared__ unsigned short Bs[64 * KP];

    int tid = threadIdx.x;
    int row0 = bid * 64;

    if (AF32) {
        const float* A = (const float*)Aptr;
        for (int c = tid; c < 64 * (KD / 4); c += 256) {
            int r = c / (KD / 4), q = c % (KD / 4);
            int gr = row0 + r;
            float4 v = make_float4(0.f, 0.f, 0.f, 0.f);
            if (gr < Crows) v = *(const float4*)(A + (size_t)gr * KD + q * 4);
            union { unsigned short s[4]; uint2 u; } pk;
            pk.s[0] = f2bf(v.x); pk.s[1] = f2bf(v.y);
            pk.s[2] = f2bf(v.z); pk.s[3] = f2bf(v.w);
            *(uint2*)&As[r * KP + q * 4] = pk.u;
        }
    } else {
        const unsigned short* A = (const unsigned short*)Aptr;
        for (int c = tid; c < 64 * (KD / 8); c += 256) {
            int r = c / (KD / 8), q = c % (KD / 8);
            int gr = row0 + r;
            sh8 v = {};
            if (gr < Crows) v = *(const sh8*)(A + (size_t)gr * KD + q * 8);
            *(sh8*)&As[r * KP + q * 8] = v;
        }
    }

    int wv = tid >> 6, lane = tid & 63;
    int lrow = lane & 15, lq = lane >> 4;

    for (int mt = 0; mt < MT; ++mt) {
        int c0 = mt * 64;
        __syncthreads();
        for (int c = tid; c < 64 * (KD / 8); c += 256) {
            int r = c / (KD / 8), q = c % (KD / 8);
            *(sh8*)&Bs[r * KP + q * 8] = *(const sh8*)(Bt + (size_t)(c0 + r) * KD + q * 8);
        }
        __syncthreads();

        floatx4 acc[4] = {{0.f,0.f,0.f,0.f},{0.f,0.f,0.f,0.f},{0.f,0.f,0.f,0.f},{0.f,0.f,0.f,0.f}};
#pragma unroll
        for (int kt = 0; kt < KD / 32; ++kt) {
            int kb = kt * 32 + lq * 8;
            sh8 a0 = *(const sh8*)&As[(wv * 16 + lrow) * KP + kb];
#pragma unroll
            for (int cf = 0; cf < 4; ++cf) {
                sh8 b = *(const sh8*)&Bs[(cf * 16 + lrow) * KP + kb];
                acc[cf] = __builtin_amdgcn_mfma_f32_16x16x32_bf16(a0, b, acc[cf], 0, 0, 0);
            }
        }

#pragma unroll
        for (int r = 0; r < 4; ++r) {
            int gr = row0 + wv * 16 + lq * 4 + r;
            if (gr >= Crows) continue;
#pragma unroll
            for (int cf = 0; cf < 4; ++cf) {
                int gc = c0 + cf * 16 + lrow;
                float val = acc[cf][r];
                if (gc < SPLIT) {
                    int pi = (gc < PW) ? gc * 2 : (gc - PW) * 2 + 1;
                    Csp[(size_t)gr * SPLIT + pi] = f2bf(val);
                } else if (gc < SPLIT + ROOTW) {
                    Croot[(size_t)gr * ROOTW + (gc - SPLIT)] = val;
                }
            }
        }
    }
}

// XCD-range-partitioned bucketed permute: cnt is both histogram and cursor.
__device__ __forceinline__ void permute_body(int b, const int* __restrict__ src,
                                             const int* __restrict__ dst,
                                             const float* __restrict__ attr,
                                             int* __restrict__ cnt,
                                             unsigned int* __restrict__ edata) {
    int range = b & 7;
    int slice = b >> 3;
    int lo = range * RANGE_SZ;
    int e0 = slice * PERM_CHUNK;
    int e1 = e0 + PERM_CHUNK;
    for (int e = e0 + (int)threadIdx.x; e < e1; e += 256) {
        int d = dst[e];
        if ((unsigned)(d - lo) < (unsigned)RANGE_SZ) {
            int pos = atomicAdd(&cnt[d], 1);
            if (pos < EST) {
                unsigned int q = (unsigned int)(attr[e] * 65535.0f + 0.5f);
                edata[d * EST + pos] = (unsigned int)src[e] | (q << 16);
            }
        }
    }
}

// ---------------- fused layer-1 GEMM + permute (independent work, one launch) ----------
__global__ __launch_bounds__(256) void gemm1_permute(const float* __restrict__ x,
                                                     const unsigned short* __restrict__ WT1,
                                                     unsigned short* __restrict__ Ysp,
                                                     float* __restrict__ Yroot,
                                                     const int* __restrict__ src,
                                                     const int* __restrict__ dst,
                                                     const float* __restrict__ attr,
                                                     int* __restrict__ cnt,
                                                     unsigned int* __restrict__ edata,
                                                     int gemmBlocks) {
    if ((int)blockIdx.x < gemmBlocks) {
        gemm_body<128, true, 128, 64, 64, 3>(blockIdx.x, (const void*)x, WT1, Ysp, Yroot, N_NODES);
    } else {
        permute_body(blockIdx.x - gemmBlocks, src, dst, attr, cnt, edata);
    }
}

// ---------------- gather layer 1: half-wave edge pairing (r7 proven) ----------
// Writes h to BOTH hb (compact, for gather2h's random reads) and A192 cols 128..191
// (for the layer-2 GEMM). Disjoint from gather2h's A192 cols 0..127.
__global__ __launch_bounds__(256) void gather1(const unsigned short* __restrict__ Ysp,
                                               const float* __restrict__ Yroot,
                                               const int* __restrict__ cnt,
                                               const unsigned int* __restrict__ edata,
                                               const float* __restrict__ bias1,
                                               unsigned short* __restrict__ h,
                                               unsigned short* __restrict__ A192) {
    int wave = (blockIdx.x * blockDim.x + threadIdx.x) >> 6;
    int lane = threadIdx.x & 63;
    if (wave >= N_NODES) return;
    int hf = lane >> 5;       // edge stream (0: even edges, 1: odd edges)
    int c  = lane & 31;       // feature pair -> features 2c, 2c+1
    int deg = cnt[wave];
    deg = deg > EST ? EST : deg;
    const unsigned int* eb = edata + (size_t)wave * EST;
    const float qs = 1.0f / 65535.0f;
    float a0 = 0.0f, a1 = 0.0f;
    if (deg <= 16) {
        unsigned int e[8]; uint2 p[8];
#pragma unroll
        for (int t = 0; t < 8; ++t) e[t] = eb[2 * t + hf];
#pragma unroll
        for (int t = 0; t < 8; ++t) {
            int idx = (2 * t + hf < deg) ? (int)(e[t] & 0xffffu) : 0;
            p[t] = *(const uint2*)(Ysp + (size_t)idx * 128 + c * 4);
        }
#pragma unroll
        for (int t = 0; t < 8; ++t) {
            float m = (2 * t + hf < deg) ? 1.0f : 0.0f;
            float v = (float)(e[t] >> 16) * qs;
            float w = 1.0f - v;
            a0 += m * (w * bf2f(p[t].x & 0xffffu) + v * bf2f(p[t].x >> 16));
            a1 += m * (w * bf2f(p[t].y & 0xffffu) + v * bf2f(p[t].y >> 16));
        }
    } else {
        unsigned int e[16]; uint2 p[16];
#pragma unroll
        for (int t = 0; t < 16; ++t) e[t] = eb[2 * t + hf];
#pragma unroll
        for (int t = 0; t < 16; ++t) {
            int idx = (2 * t + hf < deg) ? (int)(e[t] & 0xffffu) : 0;
            p[t] = *(const uint2*)(Ysp + (size_t)idx * 128 + c * 4);
        }
#pragma unroll
        for (int t = 0; t < 16; ++t) {
            float m = (2 * t + hf < deg) ? 1.0f : 0.0f;
            float v = (float)(e[t] >> 16) * qs;
            float w = 1.0f - v;
            a0 += m * (w * bf2f(p[t].x & 0xffffu) + v * bf2f(p[t].x >> 16));
            a1 += m * (w * bf2f(p[t].y & 0xffffu) + v * bf2f(p[t].y >> 16));
        }
        if (deg > 32) {  // rare (P ~ 1e-4 per node)
            for (int j = 32 + hf; j < deg; j += 2) {
                unsigned int ee = eb[j];
                int idx = (int)(ee & 0xffffu);
                uint2 pp = *(const uint2*)(Ysp + (size_t)idx * 128 + c * 4);
                float v = (float)(ee >> 16) * qs;
                float w = 1.0f - v;
                a0 += w * bf2f(pp.x & 0xffffu) + v * bf2f(pp.x >> 16);
                a1 += w * bf2f(pp.y & 0xffffu) + v * bf2f(pp.y >> 16);
            }
        }
    }
    a0 += __shfl_xor(a0, 32);
    a1 += __shfl_xor(a1, 32);
    float dg = (float)deg;
    dg = dg > 1.0f ? dg : 1.0f;
    float2 yr = *(const float2*)(Yroot + (size_t)wave * HID + c * 2);
    float2 bi = *(const float2*)(bias1 + c * 2);
    float m0 = a0 / dg + yr.x + bi.x;
    float m1 = a1 / dg + yr.y + bi.y;
    m0 = m0 > 0.0f ? m0 : expm1f(m0);  // ELU
    m1 = m1 > 0.0f ? m1 : expm1f(m1);
    if (hf == 0) {
        unsigned int u = (unsigned int)f2bf(m0) | ((unsigned int)f2bf(m1) << 16);
        *(unsigned int*)(h + (size_t)wave * HID + c * 2) = u;
        *(unsigned int*)(A192 + (size_t)wave * K2 + 128 + c * 2) = u;
    }
}

// ---------------- gather layer 2 in h-space: 128B aligned rows (2 lines/edge) ----------
// Computes agg0 = (1/deg)*sum(w*h[src]), agg1 = (1/deg)*sum(v*h[src]) and writes
// them as bf16 into A192 cols 0..127. The W2/root2 transform moves to gemm_out.
__global__ __launch_bounds__(256) void gather2h(const unsigned short* __restrict__ hb,
                                                const int* __restrict__ cnt,
                                                const unsigned int* __restrict__ edata,
                                                unsigned short* __restrict__ A192) {
    int wave = (blockIdx.x * blockDim.x + threadIdx.x) >> 6;
    int lane = threadIdx.x & 63;
    if (wave >= N_NODES) return;
    int hf = lane >> 5;       // edge stream
    int c  = lane & 31;       // feature pair -> features 2c, 2c+1 (all 32 active)
    int deg = cnt[wave];
    deg = deg > EST ? EST : deg;
    const unsigned int* eb = edata + (size_t)wave * EST;
    const float qs = 1.0f / 65535.0f;
    float a00 = 0.0f, a01 = 0.0f, a10 = 0.0f, a11 = 0.0f;  // [slot][feature-of-pair]
    if (deg <= 16) {
        unsigned int e[8], p[8];
#pragma unroll
        for (int t = 0; t < 8; ++t) e[t] = eb[2 * t + hf];
#pragma unroll
        for (int t = 0; t < 8; ++t) {
            int idx = (2 * t + hf < deg) ? (int)(e[t] & 0xffffu) : 0;
            p[t] = *(const unsigned int*)(hb + (size_t)idx * HID + c * 2);
        }
#pragma unroll
        for (int t = 0; t < 8; ++t) {
            float m = (2 * t + hf < deg) ? 1.0f : 0.0f;
            float v = (float)(e[t] >> 16) * qs;
            float wm = m * (1.0f - v), vm = m * v;
            float h0 = bf2f(p[t] & 0xffffu), h1 = bf2f(p[t] >> 16);
            a00 += wm * h0; a01 += wm * h1;
            a10 += vm * h0; a11 += vm * h1;
        }
    } else {
        unsigned int e[16], p[16];
#pragma unroll
        for (int t = 0; t < 16; ++t) e[t] = eb[2 * t + hf];
#pragma unroll
        for (int t = 0; t < 16; ++t) {
            int idx = (2 * t + hf < deg) ? (int)(e[t] & 0xffffu) : 0;
            p[t] = *(const unsigned int*)(hb + (size_t)idx * HID + c * 2);
        }
#pragma unroll
        for (int t = 0; t < 16; ++t) {
            float m = (2 * t + hf < deg) ? 1.0f : 0.0f;
            float v = (float)(e[t] >> 16) * qs;
            float wm = m * (1.0f - v), vm = m * v;
            float h0 = bf2f(p[t] & 0xffffu), h1 = bf2f(p[t] >> 16);
            a00 += wm * h0; a01 += wm * h1;
            a10 += vm * h0; a11 += vm * h1;
        }
        if (deg > 32) {
            for (int j = 32 + hf; j < deg; j += 2) {
                unsigned int ee = eb[j];
                int idx = (int)(ee & 0xffffu);
                unsigned int pp = *(const unsigned int*)(hb + (size_t)idx * HID + c * 2);
                float v = (float)(ee >> 16) * qs;
                float w = 1.0f - v;
                float h0 = bf2f(pp & 0xffffu), h1 = bf2f(pp >> 16);
                a00 += w * h0; a01 += w * h1;
                a10 += v * h0; a11 += v * h1;
            }
        }
    }
    a00 += __shfl_xor(a00, 32);
    a01 += __shfl_xor(a01, 32);
    a10 += __shfl_xor(a10, 32);
    a11 += __shfl_xor(a11, 32);
    if (hf == 0) {
        float dg = (float)deg;
        dg = dg > 1.0f ? dg : 1.0f;
        float inv = 1.0f / dg;
        unsigned int u0 = (unsigned int)f2bf(a00 * inv) | ((unsigned int)f2bf(a01 * inv) << 16);
        unsigned int u1 = (unsigned int)f2bf(a10 * inv) | ((unsigned int)f2bf(a11 * inv) << 16);
        *(unsigned int*)(A192 + (size_t)wave * K2 + c * 2) = u0;
        *(unsigned int*)(A192 + (size_t)wave * K2 + 64 + c * 2) = u1;
    }
}

// ---------------- layer-2 output GEMM: [agg0|agg1|h] (50000x192) x WT2 (192x40) ----------
// Direct f32 out + bias2. Replaces old gemm2 + the Zsp/Zroot round trip.
__global__ __launch_bounds__(256) void gemm_out(const unsigned short* __restrict__ A,
                                                const unsigned short* __restrict__ Bt,
                                                const float* __restrict__ bias2,
                                                float* __restrict__ out) {
    constexpr int KD = K2, KP = KD + 8;
    __shared__ unsigned short As[64 * KP];
    __shared__ unsigned short Bs[64 * KP];

    int tid = threadIdx.x;
    int row0 = blockIdx.x * 64;

    for (int c = tid; c < 64 * (KD / 8); c += 256) {
        int r = c / (KD / 8), q = c % (KD / 8);
        int gr = row0 + r;
        sh8 v = {};
        if (gr < N_NODES) v = *(const sh8*)(A + (size_t)gr * KD + q * 8);
        *(sh8*)&As[r * KP + q * 8] = v;
    }
    for (int c = tid; c < 64 * (KD / 8); c += 256) {
        int r = c / (KD / 8), q = c % (KD / 8);
        sh8 v = {};
        if (r < N_CLS) v = *(const sh8*)(Bt + (size_t)r * KD + q * 8);
        *(sh8*)&Bs[r * KP + q * 8] = v;
    }
    __syncthreads();

    int wv = tid >> 6, lane = tid & 63;
    int lrow = lane & 15, lq = lane >> 4;

    floatx4 acc[4] = {{0.f,0.f,0.f,0.f},{0.f,0.f,0.f,0.f},{0.f,0.f,0.f,0.f},{0.f,0.f,0.f,0.f}};
#pragma unroll
    for (int kt = 0; kt < KD / 32; ++kt) {
        int kb = kt * 32 + lq * 8;
        sh8 a0 = *(const sh8*)&As[(wv * 16 + lrow) * KP + kb];
#pragma unroll
        for (int cf = 0; cf < 4; ++cf) {
            sh8 b = *(const sh8*)&Bs[(cf * 16 + lrow) * KP + kb];
            acc[cf] = __builtin_amdgcn_mfma_f32_16x16x32_bf16(a0, b, acc[cf], 0, 0, 0);
        }
    }

#pragma unroll
    for (int r = 0; r < 4; ++r) {
        int gr = row0 + wv * 16 + lq * 4 + r;
        if (gr >= N_NODES) continue;
#pragma unroll
        for (int cf = 0; cf < 4; ++cf) {
            int gc = cf * 16 + lrow;
            if (gc < N_CLS) {
                out[(size_t)gr * N_CLS + gc] = acc[cf][r] + bias2[gc];
            }
        }
    }
}

extern "C" void kernel_launch(void* const* d_in, const int* in_sizes, int n_in,
                              void* d_out, int out_size, void* d_ws, size_t ws_size,
                              hipStream_t stream) {
    const float* x     = (const float*)d_in[0];
    const int*   eidx  = (const int*)d_in[1];
    const float* eattr = (const float*)d_in[2];
    const float* W1    = (const float*)d_in[3];
    const float* root1 = (const float*)d_in[4];
    const float* bias1 = (const float*)d_in[5];
    const float* W2    = (const float*)d_in[6];
    const float* root2 = (const float*)d_in[7];
    const float* bias2 = (const float*)d_in[8];
    float* out = (float*)d_out;

    const int* src = eidx;
    const int* dst = eidx + N_EDGES;

    // workspace layout (bytes)
    char* base = (char*)d_ws;
    unsigned short* Ysp   = (unsigned short*)base;               // 50000*128*2 = 12,800,000
    float*          Yroot = (float*)(base + 12800000);           // 50000*64*4 = 12,800,000
    unsigned short* hb    = (unsigned short*)(base + 25600000);  // 50000*64*2 = 6,400,000
    unsigned short* WT1   = (unsigned short*)(base + 32000000);  // 192*128*2 = 49,152
    unsigned short* WT2   = (unsigned short*)(base + 32049152);  // 40*192*2 = 15,360
    unsigned int*   edata = (unsigned int*)(base + 32065536);    // 50000*64*4 = 12,800,000
    int*            cnt   = (int*)(base + 44865536);             // 50,000*4 = 200,000
    unsigned short* A192  = (unsigned short*)(base + 45065536);  // 50000*192*2 = 19,200,000

    const int GB = (N_NODES + 63) / 64;  // 782 gemm blocks

    // ---- weights + cnt zeroing ----
    hipLaunchKernelGGL(concat_w, dim3((NW + N_NODES + 255) / 256), dim3(256), 0, stream,
                       W1, root1, W2, root2, WT1, WT2, cnt);

    // ---- layer-1 GEMM fused with bucketed permute ----
    hipLaunchKernelGGL(gemm1_permute, dim3(GB + 8 * PERM_SLICES), dim3(256), 0, stream,
                       x, WT1, Ysp, Yroot, src, dst, eattr, cnt, edata, GB);

    // ---- layer-1 gather (+ h into A192 cols 128..191) ----
    hipLaunchKernelGGL(gather1, dim3((N_NODES * 64 + 255) / 256), dim3(256), 0, stream,
                       Ysp, Yroot, cnt, edata, bias1, hb, A192);

    // ---- layer-2 gather in h-space (agg0/agg1 into A192 cols 0..127) ----
    hipLaunchKernelGGL(gather2h, dim3((N_NODES * 64 + 255) / 256), dim3(256), 0, stream,
                       hb, cnt, edata, A192);

    // ---- layer-2 output GEMM (W2 + root2 + bias2 fused, f32 out) ----
    hipLaunchKernelGGL(gemm_out, dim3(GB), dim3(256), 0, stream,
                       A192, WT2, bias2, out);
}